// Round 6
// baseline (570.383 us; speedup 1.0000x reference)
//
#include <hip/hip_runtime.h>
#include <hip/hip_bf16.h>
#include <float.h>

#define HEADS 4
#define HID 64
#define HC 256   // HEADS*HID
#define NEG_SLOPE 0.2f
#define EPS 1e-16f
#define SLOG 7           // log2 slots per node
#define SLOTS 128        // fixed adjacency slots per node (max in-deg ~45)

typedef short bf16x8 __attribute__((ext_vector_type(8)));
typedef float f32x4 __attribute__((ext_vector_type(4)));
typedef unsigned short ushort8 __attribute__((ext_vector_type(8)));

__device__ __forceinline__ float bflo(unsigned u) { return __uint_as_float(u << 16); }
__device__ __forceinline__ float bfhi(unsigned u) { return __uint_as_float(u & 0xffff0000u); }
__device__ __forceinline__ unsigned packbf2(float a, float b) {
  __hip_bfloat16 ha = __float2bfloat16(a), hb = __float2bfloat16(b);
  unsigned short ua = *reinterpret_cast<unsigned short*>(&ha);
  unsigned short ub = *reinterpret_cast<unsigned short*>(&hb);
  return (unsigned)ua | ((unsigned)ub << 16);
}

#define PK 40  // padded LDS row stride (bf16 elems) — proven conflict-light

// ---------------------------------------------------------------------------
// Conv GEMM (R6/R7 proven body). R11 change: C is written SLICE-MAJOR
// (hb[slice=col/32][node][32]) so gat_aggregate_sl's per-XCD slice is a
// contiguous 3.2MB block that fits a 4MB XCD L2. Only the C-write address
// changed; GEMM body and attn-coef epilogue untouched.
// ---------------------------------------------------------------------------
__global__ void __launch_bounds__(256) conv_gemm_attn(
    const __hip_bfloat16* __restrict__ A, const __hip_bfloat16* __restrict__ Bt,
    __hip_bfloat16* __restrict__ Cb,
    const float* __restrict__ att_s, const float* __restrict__ att_d,
    float* __restrict__ a_s, float* __restrict__ a_d,
    float* __restrict__ blockmax, int M, int K) {
  __shared__ unsigned short As[2][64 * PK];
  __shared__ unsigned short Bs[2][256 * PK];
  int tid = threadIdx.x;
  int lane = tid & 63, w = tid >> 6;
  int col16 = lane & 15, quad = lane >> 4;
  int row0 = blockIdx.x * 64;
  const unsigned short* Ag = (const unsigned short*)A;
  const unsigned short* Bg = (const unsigned short*)Bt;

  int ar = tid >> 2;
  int ako = (tid & 3) << 3;
  int agr = row0 + ar; if (agr >= M) agr = M - 1;
  const unsigned short* aga = Ag + (size_t)agr * K + ako;

  f32x4 acc[4][4] = {};
  int niter = K >> 5;

  ushort8 pa, pb[4];
  pa = *(const ushort8*)(aga);
#pragma unroll
  for (int p = 0; p < 4; p++) {
    int i2 = tid + (p << 8);
    int br = i2 >> 2, bko = (i2 & 3) << 3;
    pb[p] = *(const ushort8*)(Bg + (size_t)br * K + bko);
  }
  *(ushort8*)(&As[0][ar * PK + ako]) = pa;
#pragma unroll
  for (int p = 0; p < 4; p++) {
    int i2 = tid + (p << 8);
    int br = i2 >> 2, bko = (i2 & 3) << 3;
    *(ushort8*)(&Bs[0][br * PK + bko]) = pb[p];
  }
  __syncthreads();

  for (int it = 0; it < niter; ++it) {
    int cur = it & 1, nxt = cur ^ 1;
    int k1 = (it + 1) << 5;
    if (it + 1 < niter) {
      pa = *(const ushort8*)(aga + k1);
#pragma unroll
      for (int p = 0; p < 4; p++) {
        int i2 = tid + (p << 8);
        int br = i2 >> 2, bko = (i2 & 3) << 3;
        pb[p] = *(const ushort8*)(Bg + (size_t)br * K + k1 + bko);
      }
    }
    bf16x8 a[4], b[4];
#pragma unroll
    for (int i = 0; i < 4; i++)
      a[i] = *(const bf16x8*)(&As[cur][(i * 16 + col16) * PK + quad * 8]);
#pragma unroll
    for (int j = 0; j < 4; j++)
      b[j] = *(const bf16x8*)(&Bs[cur][((w << 6) + j * 16 + col16) * PK + quad * 8]);
#pragma unroll
    for (int i = 0; i < 4; i++)
#pragma unroll
      for (int j = 0; j < 4; j++)
        acc[i][j] = __builtin_amdgcn_mfma_f32_16x16x32_bf16(a[i], b[j], acc[i][j], 0, 0, 0);
    if (it + 1 < niter) {
      *(ushort8*)(&As[nxt][ar * PK + ako]) = pa;
#pragma unroll
      for (int p = 0; p < 4; p++) {
        int i2 = tid + (p << 8);
        int br = i2 >> 2, bko = (i2 & 3) << 3;
        *(ushort8*)(&Bs[nxt][br * PK + bko]) = pb[p];
      }
    }
    __syncthreads();
  }

  // slice-major C-write: col gc -> slice gc>>5, offset gc&31
#pragma unroll
  for (int i = 0; i < 4; i++) {
#pragma unroll
    for (int j = 0; j < 4; j++) {
      int gc = (w << 6) + j * 16 + col16;
      size_t sbase = ((size_t)(gc >> 5) * M) * 32 + (gc & 31);
      int grb = row0 + i * 16 + quad * 4;
#pragma unroll
      for (int r = 0; r < 4; r++) {
        int gr = grb + r;
        if (gr < M) Cb[sbase + (size_t)gr * 32] = __float2bfloat16(acc[i][j][r]);
      }
    }
  }

  float ws4[4], wd4[4];
#pragma unroll
  for (int j = 0; j < 4; j++) {
    ws4[j] = att_s[(w << 6) + j * 16 + col16];
    wd4[j] = att_d[(w << 6) + j * 16 + col16];
  }
  float wavemax = -FLT_MAX;
#pragma unroll
  for (int i = 0; i < 4; i++) {
#pragma unroll
    for (int r = 0; r < 4; r++) {
      float vs = 0.f, vd = 0.f;
#pragma unroll
      for (int j = 0; j < 4; j++) {
        vs += acc[i][j][r] * ws4[j];
        vd += acc[i][j][r] * wd4[j];
      }
#pragma unroll
      for (int off = 1; off < 16; off <<= 1) {
        vs += __shfl_xor(vs, off);
        vd += __shfl_xor(vd, off);
      }
      int gr = row0 + i * 16 + quad * 4 + r;
      if (col16 == 0 && gr < M) {
        a_s[(size_t)gr * 4 + w] = vs;
        a_d[(size_t)gr * 4 + w] = vd;
      }
      wavemax = fmaxf(wavemax, vs);
    }
  }
  wavemax = fmaxf(wavemax, __shfl_xor(wavemax, 16));
  wavemax = fmaxf(wavemax, __shfl_xor(wavemax, 32));
  if (lane == 0) blockmax[(size_t)blockIdx.x * 4 + w] = wavemax;
}

// reduce blockmax[nb][4] -> gmaxf[goff+0..3]  (~2us, no fence in hot kernel)
__global__ void __launch_bounds__(256) reduce_gmax(const float* __restrict__ blockmax,
                                                   float* __restrict__ gmaxf, int goff, int nb) {
  __shared__ float wm[4][4];
  int tid = threadIdx.x, lane = tid & 63, w = tid >> 6;
  int hd = tid & 3;
  float m = -FLT_MAX;
  for (int i = tid >> 2; i < nb; i += 64)
    m = fmaxf(m, blockmax[(size_t)i * 4 + hd]);
#pragma unroll
  for (int off = 4; off < 64; off <<= 1)
    m = fmaxf(m, __shfl_xor(m, off));
  if (lane < 4) wm[w][lane] = m;
  __syncthreads();
  if (tid < 4) {
    float r = fmaxf(fmaxf(wm[0][tid], wm[1][tid]), fmaxf(wm[2][tid], wm[3][tid]));
    gmaxf[goff + tid] = r;
  }
}

// ---------------------------------------------------------------------------
// Fused post_mp with dbuf stage 1 (R7 proven). Reads aggb ROW-major (the
// aggregate still writes row-major output) — untouched.
// ---------------------------------------------------------------------------
#define TS 72

__global__ void __launch_bounds__(256) postmp_fused(
    const __hip_bfloat16* __restrict__ A, const __hip_bfloat16* __restrict__ Wm1t,
    const __hip_bfloat16* __restrict__ Wm2t, const float* __restrict__ bm1,
    const float* __restrict__ bm2, float* __restrict__ out, int M) {
  __shared__ unsigned short smem[24576];
  unsigned short* W2s = &smem[15360];
  int tid = threadIdx.x;
  int lane = tid & 63, w = tid >> 6;
  int col16 = lane & 15, quad = lane >> 4;
  int row0 = blockIdx.x * 128;
  const unsigned short* Ag = (const unsigned short*)A;
  const unsigned short* Bg = (const unsigned short*)Wm1t;
  const unsigned short* W2g = (const unsigned short*)Wm2t;

#pragma unroll
  for (int c = tid; c < 1024; c += 256) {
    int r = c >> 3, ko = (c & 7) << 3;
    ushort8 v = {};
    if (r < 121) v = *(const ushort8*)(W2g + (size_t)r * 64 + ko);
    *(ushort8*)(&W2s[r * TS + ko]) = v;
  }

  int ar0 = tid >> 2, ako = (tid & 3) << 3;
  int agr0 = row0 + ar0;       if (agr0 >= M) agr0 = M - 1;
  int agr1 = row0 + ar0 + 64;  if (agr1 >= M) agr1 = M - 1;
  const unsigned short* aga0 = Ag + (size_t)agr0 * 256 + ako;
  const unsigned short* aga1 = Ag + (size_t)agr1 * 256 + ako;
  int br = tid >> 2, bko = (tid & 3) << 3;
  const unsigned short* bga = Bg + (size_t)br * 256 + bko;

  f32x4 acc1[2][4] = {};
  ushort8 pa0, pa1, pbv;
  pa0 = *(const ushort8*)(aga0);
  pa1 = *(const ushort8*)(aga1);
  pbv = *(const ushort8*)(bga);
  *(ushort8*)(&smem[ar0 * PK + ako]) = pa0;
  *(ushort8*)(&smem[(ar0 + 64) * PK + ako]) = pa1;
  *(ushort8*)(&smem[10240 + br * PK + bko]) = pbv;
  __syncthreads();

  for (int it = 0; it < 8; ++it) {
    int cur = it & 1, nxt = cur ^ 1;
    unsigned short* Asc = &smem[cur * 5120];
    unsigned short* Bsc = &smem[10240 + cur * 2560];
    int k1 = (it + 1) << 5;
    if (it + 1 < 8) {
      pa0 = *(const ushort8*)(aga0 + k1);
      pa1 = *(const ushort8*)(aga1 + k1);
      pbv = *(const ushort8*)(bga + k1);
    }
    bf16x8 a[2], b[4];
#pragma unroll
    for (int i = 0; i < 2; i++)
      a[i] = *(const bf16x8*)(&Asc[(w * 32 + i * 16 + col16) * PK + quad * 8]);
#pragma unroll
    for (int j = 0; j < 4; j++)
      b[j] = *(const bf16x8*)(&Bsc[(j * 16 + col16) * PK + quad * 8]);
#pragma unroll
    for (int i = 0; i < 2; i++)
#pragma unroll
      for (int j = 0; j < 4; j++)
        acc1[i][j] = __builtin_amdgcn_mfma_f32_16x16x32_bf16(a[i], b[j], acc1[i][j], 0, 0, 0);
    if (it + 1 < 8) {
      unsigned short* Asn = &smem[nxt * 5120];
      unsigned short* Bsn = &smem[10240 + nxt * 2560];
      *(ushort8*)(&Asn[ar0 * PK + ako]) = pa0;
      *(ushort8*)(&Asn[(ar0 + 64) * PK + ako]) = pa1;
      *(ushort8*)(&Bsn[br * PK + bko]) = pbv;
    }
    __syncthreads();
  }

  unsigned short* T = &smem[0];
#pragma unroll
  for (int i = 0; i < 2; i++) {
#pragma unroll
    for (int j = 0; j < 4; j++) {
      int col = j * 16 + col16;
      float bv = bm1[col];
#pragma unroll
      for (int r = 0; r < 4; r++) {
        int rl = w * 32 + i * 16 + quad * 4 + r;
        __hip_bfloat16 hv = __float2bfloat16(acc1[i][j][r] + bv);
        T[rl * TS + col] = *reinterpret_cast<unsigned short*>(&hv);
      }
    }
  }
  __syncthreads();

  int wm2 = w & 1, wn2 = w >> 1;
  f32x4 acc2[4][4] = {};
#pragma unroll
  for (int kk = 0; kk < 2; kk++) {
    bf16x8 a[4], b[4];
#pragma unroll
    for (int i = 0; i < 4; i++)
      a[i] = *(const bf16x8*)(&T[(wm2 * 64 + i * 16 + col16) * TS + kk * 32 + quad * 8]);
#pragma unroll
    for (int j = 0; j < 4; j++)
      b[j] = *(const bf16x8*)(&W2s[(wn2 * 64 + j * 16 + col16) * TS + kk * 32 + quad * 8]);
#pragma unroll
    for (int i = 0; i < 4; i++)
#pragma unroll
      for (int j = 0; j < 4; j++)
        acc2[i][j] = __builtin_amdgcn_mfma_f32_16x16x32_bf16(a[i], b[j], acc2[i][j], 0, 0, 0);
  }
#pragma unroll
  for (int i = 0; i < 4; i++) {
#pragma unroll
    for (int j = 0; j < 4; j++) {
      int gc = wn2 * 64 + j * 16 + col16;
      if (gc >= 121) continue;
      float bv = bm2[gc];
      int grb = row0 + wm2 * 64 + i * 16 + quad * 4;
#pragma unroll
      for (int r = 0; r < 4; r++) {
        int gr = grb + r;
        if (gr >= M) continue;
        float v = acc2[i][j][r] + bv;
        out[(size_t)gr * 121 + gc] = 1.f / (1.f + __expf(-v));
      }
    }
  }
}

// ---------------------------------------------------------------------------
// setup: x cast + all weight transposes + slot/cursor init, one kernel.
// ---------------------------------------------------------------------------
__global__ void setup_all(const float* __restrict__ x, __hip_bfloat16* __restrict__ xb,
                          const float* __restrict__ W1, const float* __restrict__ W2,
                          const float* __restrict__ Wm1, const float* __restrict__ Wm2,
                          __hip_bfloat16* __restrict__ W1t, __hip_bfloat16* __restrict__ W2t,
                          __hip_bfloat16* __restrict__ Wm1t, __hip_bfloat16* __restrict__ Wm2t,
                          int* __restrict__ cur, int* __restrict__ slots,
                          int n, int castBlocks, int prepBlocks) {
  int b = blockIdx.x;
  int tid = threadIdx.x;
  if (b < castBlocks) {  // cast x -> xb (float4 -> bf16x4)
    int i = b * 256 + tid;
    if (i < n * 32) {
      float4 v = *(const float4*)(x + 4 * (size_t)i);
      uint2 pk;
      pk.x = packbf2(v.x, v.y);
      pk.y = packbf2(v.z, v.w);
      *(uint2*)((unsigned*)xb + 2 * (size_t)i) = pk;
    }
    return;
  }
  b -= castBlocks;
  if (b < prepBlocks) {  // weight transposes
    int i = b * 256 + tid;
    if (i < 128 * 256) {
      int nn = i / 128, kk = i - nn * 128;
      W1t[i] = __float2bfloat16(W1[(size_t)kk * 256 + nn]);
      return;
    }
    i -= 128 * 256;
    if (i < 256 * 256) {
      int nn = i / 256, kk = i - nn * 256;
      W2t[i] = __float2bfloat16(W2[(size_t)kk * 256 + nn]);
      return;
    }
    i -= 256 * 256;
    if (i < 256 * 64) {
      int nn = i / 256, kk = i - nn * 256;
      Wm1t[i] = __float2bfloat16(Wm1[(size_t)kk * 64 + nn]);
      return;
    }
    i -= 256 * 64;
    if (i < 64 * 121) {
      int nn = i / 64, kk = i - nn * 64;
      Wm2t[i] = __float2bfloat16(Wm2[(size_t)kk * 121 + nn]);
    }
    return;
  }
  b -= prepBlocks;
  {  // slot init: self-loop in slot 0, cursor = 1
    int i = b * 256 + tid;
    if (i < n) {
      cur[i] = 1;
      slots[(size_t)i << SLOG] = i;
    }
  }
}

// fill adjacency slots (dst-bucketed, unordered)
__global__ void slot_fill(const int* __restrict__ ei, int E,
                          int* __restrict__ cur, int* __restrict__ slots) {
  int i = blockIdx.x * 256 + threadIdx.x;
  if (i >= E) return;
  int s = ei[i], d = ei[E + i];
  int pos = atomicAdd(&cur[d], 1);
  slots[((size_t)d << SLOG) + pos] = s;
}

// ---------------------------------------------------------------------------
// GAT aggregation — R12: XCD-pinned column slices (R11 + denominator fix).
// R11 BUG: rq used lq*0.25, but the egrp xor-reduction (offsets 4..32)
// already counts each edge exactly ONCE per lsub class — the 4 lsub lanes
// sharing an edge are in disjoint reduction classes. Fix: rq = 1/(lq+EPS).
// Theory unchanged: slice = blockIdx&7 pins each contiguous 3.2MB slice-major
// slice to one XCD L2; FETCH should drop 209MB -> ~30-60MB.
// ---------------------------------------------------------------------------
__global__ void __launch_bounds__(256) gat_aggregate_sl(
    const __hip_bfloat16* __restrict__ hbs,   // slice-major [8][n][32]
    const float* __restrict__ a_src, const float* __restrict__ a_dst,
    const int* __restrict__ cnt_arr, const int* __restrict__ slots,
    const float* __restrict__ bias, const float* __restrict__ gmaxf, int goff,
    __hip_bfloat16* __restrict__ out, int n) {
  int tid = threadIdx.x;
  int wid = tid >> 6, lane = tid & 63;
  int slice = blockIdx.x & 7;               // low bits -> XCD round-robin
  int node = ((blockIdx.x >> 3) << 2) + wid;
  if (node >= n) return;
  int head = slice >> 1;                    // 32 cols/slice, 64 cols/head
  int lsub = lane & 3;                      // 16B sub-chunk within 64B slice
  int egrp = lane >> 2;                     // edge offset within step (0..15)

  float advh = a_dst[(size_t)node * 4 + head];
  float mh = gmaxf[goff + head] + advh; mh = fmaxf(mh, NEG_SLOPE * mh);
  int cntN = __builtin_amdgcn_readfirstlane(cnt_arr[node]);
  int beg = node << SLOG;
  const uint4* hw4 = (const uint4*)hbs + (size_t)slice * n * 4 + lsub;

  float lq = 0.f;
  float c0 = 0.f, c1 = 0.f, c2 = 0.f, c3 = 0.f;
  float c4 = 0.f, c5 = 0.f, c6 = 0.f, c7 = 0.f;

  for (int cbeg = 0; cbeg < cntN; cbeg += 64) {
    int cnt = cntN - cbeg; if (cnt > 64) cnt = 64;
    int eidx = beg + cbeg + (lane < cnt ? lane : cnt - 1);
    int s_l = slots[eidx];
    float av = a_src[(size_t)s_l * 4 + head];   // 800KB table, L2-hot
    float v = av + advh; v = fmaxf(v, NEG_SLOPE * v);
    float p_l = (lane < cnt) ? __expf(v - mh) : 0.f;  // dup lanes -> 0

    for (int j = 0; j < cnt; j += 16) {       // 16 edges per step
      int jc = j + egrp;                      // <= 63 always
      int sj = __shfl(s_l, jc);
      float pq = __shfl(p_l, jc);
      uint4 d = hw4[(size_t)sj * 4];
      c0 += pq * bflo(d.x); c1 += pq * bfhi(d.x);
      c2 += pq * bflo(d.y); c3 += pq * bfhi(d.y);
      c4 += pq * bflo(d.z); c5 += pq * bfhi(d.z);
      c6 += pq * bflo(d.w); c7 += pq * bfhi(d.w);
      lq += pq;
    }
  }

  // reduce across the 16 edge-groups (lanes with equal lane&3);
  // each edge is counted exactly once per lsub class after this.
#pragma unroll
  for (int off = 4; off <= 32; off <<= 1) {
    lq += __shfl_xor(lq, off);
    c0 += __shfl_xor(c0, off); c1 += __shfl_xor(c1, off);
    c2 += __shfl_xor(c2, off); c3 += __shfl_xor(c3, off);
    c4 += __shfl_xor(c4, off); c5 += __shfl_xor(c5, off);
    c6 += __shfl_xor(c6, off); c7 += __shfl_xor(c7, off);
  }

  if (lane < 4) {
    int cb = slice * 32 + lane * 8;           // lsub == lane here
    float4 bA = *(const float4*)(bias + cb);
    float4 bB = *(const float4*)(bias + cb + 4);
    float rq = 1.f / (lq + EPS);              // R12 fix: lq is already 1x
    float o0 = fmaxf(c0 * rq + bA.x, 0.f);
    float o1 = fmaxf(c1 * rq + bA.y, 0.f);
    float o2 = fmaxf(c2 * rq + bA.z, 0.f);
    float o3 = fmaxf(c3 * rq + bA.w, 0.f);
    float o4 = fmaxf(c4 * rq + bB.x, 0.f);
    float o5 = fmaxf(c5 * rq + bB.y, 0.f);
    float o6 = fmaxf(c6 * rq + bB.z, 0.f);
    float o7 = fmaxf(c7 * rq + bB.w, 0.f);
    uint4 pk;
    pk.x = packbf2(o0, o1);
    pk.y = packbf2(o2, o3);
    pk.z = packbf2(o4, o5);
    pk.w = packbf2(o6, o7);
    // out stays ROW-major (consumed by conv2 GEMM / postmp)
    *(uint4*)((unsigned*)out + (size_t)node * 128 + (cb >> 1)) = pk;
  }
}

// ---------------------------------------------------------------------------
extern "C" void kernel_launch(void* const* d_in, const int* in_sizes, int n_in,
                              void* d_out, int out_size, void* d_ws, size_t ws_size,
                              hipStream_t stream) {
  const float* x      = (const float*)d_in[0];
  const int*   ei     = (const int*)d_in[1];
  const float* W1     = (const float*)d_in[2];
  const float* att_s1 = (const float*)d_in[3];
  const float* att_d1 = (const float*)d_in[4];
  const float* b1     = (const float*)d_in[5];
  const float* W2     = (const float*)d_in[6];
  const float* att_s2 = (const float*)d_in[7];
  const float* att_d2 = (const float*)d_in[8];
  const float* b2     = (const float*)d_in[9];
  const float* Wm1    = (const float*)d_in[10];
  const float* bm1    = (const float*)d_in[11];
  const float* Wm2    = (const float*)d_in[12];
  const float* bm2    = (const float*)d_in[13];
  float* out = (float*)d_out;

  int n = in_sizes[0] / 128;   // 50000
  int E = in_sizes[1] / 2;     // 800000

  char* ws = (char*)d_ws;
  size_t off = 0;
  auto carve = [&](size_t bytes) {
    char* p = ws + off;
    off += (bytes + 255) & ~(size_t)255;
    return p;
  };
  __hip_bfloat16* hb   = (__hip_bfloat16*)carve((size_t)n * HC * 2);   // slice-major
  __hip_bfloat16* aggb = (__hip_bfloat16*)carve((size_t)n * HC * 2);   // row-major
  __hip_bfloat16* xb   = (__hip_bfloat16*)carve((size_t)n * 128 * 2);
  __hip_bfloat16* W1t  = (__hip_bfloat16*)carve((size_t)128 * HC * 2);
  __hip_bfloat16* W2t  = (__hip_bfloat16*)carve((size_t)HC * HC * 2);
  __hip_bfloat16* Wm1t = (__hip_bfloat16*)carve((size_t)HC * HID * 2);
  __hip_bfloat16* Wm2t = (__hip_bfloat16*)carve((size_t)HID * 121 * 2);
  float* as    = (float*)carve((size_t)n * HEADS * 4);
  float* ad    = (float*)carve((size_t)n * HEADS * 4);
  int*   cur   = (int*)carve((size_t)n * 4);
  int*   slots = (int*)carve(((size_t)n << SLOG) * 4);
  float* blockmax = (float*)carve((size_t)((n + 63) / 64) * 4 * 4);
  float* gmaxf    = (float*)carve((size_t)8 * 4);
  (void)ws_size;

  int rows64 = (n + 63) / 64;
  int castBlocks = (n * 32 + 255) / 256;            // 6250
  int prepBlocks = (122432 + 255) / 256;            // 479
  int slotBlocks = (n + 255) / 256;                 // 196
  int aggBlocks = ((n + 3) / 4) * 8;                // node-groups x 8 slices

  // 1: setup (cast + transposes + slot init)
  setup_all<<<castBlocks + prepBlocks + slotBlocks, 256, 0, stream>>>(
      x, xb, W1, W2, Wm1, Wm2, W1t, W2t, Wm1t, Wm2t, cur, slots,
      n, castBlocks, prepBlocks);
  // 2: adjacency fill
  slot_fill<<<(E + 255) / 256, 256, 0, stream>>>(ei, E, cur, slots);

  // 3: conv1 (+ fused attn coefs), writes hb slice-major
  conv_gemm_attn<<<rows64, 256, 0, stream>>>(
      xb, W1t, hb, att_s1, att_d1, as, ad, blockmax, n, 128);
  // 4: gmax reduce
  reduce_gmax<<<1, 256, 0, stream>>>(blockmax, gmaxf, 0, rows64);
  // 5: aggregate 1 (slice-per-XCD)
  gat_aggregate_sl<<<aggBlocks, 256, 0, stream>>>(hb, as, ad, cur, slots, b1, gmaxf, 0, aggb, n);

  // 6: conv2 (reads aggb row-major, writes hb slice-major)
  conv_gemm_attn<<<rows64, 256, 0, stream>>>(
      aggb, W2t, hb, att_s2, att_d2, as, ad, blockmax, n, HC);
  // 7: gmax reduce
  reduce_gmax<<<1, 256, 0, stream>>>(blockmax, gmaxf, 4, rows64);
  // 8: aggregate 2
  gat_aggregate_sl<<<aggBlocks, 256, 0, stream>>>(hb, as, ad, cur, slots, b2, gmaxf, 4, aggb, n);

  // 9: post_mp
  postmp_fused<<<(n + 127) / 128, 256, 0, stream>>>(aggb, Wm1t, Wm2t, bm1, bm2, out, n);
}

// Round 9
// 406.514 us; speedup vs baseline: 1.4031x; 1.4031x over previous
//
#include <hip/hip_runtime.h>
#include <hip/hip_bf16.h>
#include <float.h>

#define HEADS 4
#define HID 64
#define HC 256   // HEADS*HID
#define NEG_SLOPE 0.2f
#define EPS 1e-16f
#define SLOG 7           // log2 slots per node
#define SLOTS 128        // fixed adjacency slots per node (max in-deg ~45)

typedef short bf16x8 __attribute__((ext_vector_type(8)));
typedef float f32x4 __attribute__((ext_vector_type(4)));
typedef unsigned short ushort8 __attribute__((ext_vector_type(8)));

__device__ __forceinline__ float bflo(unsigned u) { return __uint_as_float(u << 16); }
__device__ __forceinline__ float bfhi(unsigned u) { return __uint_as_float(u & 0xffff0000u); }
__device__ __forceinline__ unsigned packbf2(float a, float b) {
  __hip_bfloat16 ha = __float2bfloat16(a), hb = __float2bfloat16(b);
  unsigned short ua = *reinterpret_cast<unsigned short*>(&ha);
  unsigned short ub = *reinterpret_cast<unsigned short*>(&hb);
  return (unsigned)ua | ((unsigned)ub << 16);
}

// IEEE754 total-order key for unsigned atomicMax (exact, bijective)
__device__ __forceinline__ unsigned fkey(float f) {
  unsigned u = __float_as_uint(f);
  return (u >> 31) ? ~u : (u | 0x80000000u);
}
__device__ __forceinline__ float fdec(unsigned k) {
  unsigned u = (k >> 31) ? (k & 0x7FFFFFFFu) : ~k;
  return __uint_as_float(u);
}

#define PK 40  // padded LDS row stride (bf16 elems) — proven conflict-light

// ---------------------------------------------------------------------------
// Conv GEMM (R6/R7 proven body, ROW-major C — R11/R12 slice-major reverted:
// slicing halved FETCH but 8x'd wave overhead, 64.5 -> 186us). R13 change:
// blockmax store + separate reduce_gmax replaced by key-atomicMax into
// gmax_u[4] (782x4 atomics on 4 addrs, launch-order visibility, no fence —
// R8 lesson respected).
// ---------------------------------------------------------------------------
__global__ void __launch_bounds__(256) conv_gemm_attn(
    const __hip_bfloat16* __restrict__ A, const __hip_bfloat16* __restrict__ Bt,
    __hip_bfloat16* __restrict__ Cb,
    const float* __restrict__ att_s, const float* __restrict__ att_d,
    float* __restrict__ a_s, float* __restrict__ a_d,
    unsigned* __restrict__ gmax_u, int M, int K) {
  __shared__ unsigned short As[2][64 * PK];
  __shared__ unsigned short Bs[2][256 * PK];
  int tid = threadIdx.x;
  int lane = tid & 63, w = tid >> 6;
  int col16 = lane & 15, quad = lane >> 4;
  int row0 = blockIdx.x * 64;
  const unsigned short* Ag = (const unsigned short*)A;
  const unsigned short* Bg = (const unsigned short*)Bt;

  int ar = tid >> 2;
  int ako = (tid & 3) << 3;
  int agr = row0 + ar; if (agr >= M) agr = M - 1;
  const unsigned short* aga = Ag + (size_t)agr * K + ako;

  f32x4 acc[4][4] = {};
  int niter = K >> 5;

  ushort8 pa, pb[4];
  pa = *(const ushort8*)(aga);
#pragma unroll
  for (int p = 0; p < 4; p++) {
    int i2 = tid + (p << 8);
    int br = i2 >> 2, bko = (i2 & 3) << 3;
    pb[p] = *(const ushort8*)(Bg + (size_t)br * K + bko);
  }
  *(ushort8*)(&As[0][ar * PK + ako]) = pa;
#pragma unroll
  for (int p = 0; p < 4; p++) {
    int i2 = tid + (p << 8);
    int br = i2 >> 2, bko = (i2 & 3) << 3;
    *(ushort8*)(&Bs[0][br * PK + bko]) = pb[p];
  }
  __syncthreads();

  for (int it = 0; it < niter; ++it) {
    int cur = it & 1, nxt = cur ^ 1;
    int k1 = (it + 1) << 5;
    if (it + 1 < niter) {
      pa = *(const ushort8*)(aga + k1);
#pragma unroll
      for (int p = 0; p < 4; p++) {
        int i2 = tid + (p << 8);
        int br = i2 >> 2, bko = (i2 & 3) << 3;
        pb[p] = *(const ushort8*)(Bg + (size_t)br * K + k1 + bko);
      }
    }
    bf16x8 a[4], b[4];
#pragma unroll
    for (int i = 0; i < 4; i++)
      a[i] = *(const bf16x8*)(&As[cur][(i * 16 + col16) * PK + quad * 8]);
#pragma unroll
    for (int j = 0; j < 4; j++)
      b[j] = *(const bf16x8*)(&Bs[cur][((w << 6) + j * 16 + col16) * PK + quad * 8]);
#pragma unroll
    for (int i = 0; i < 4; i++)
#pragma unroll
      for (int j = 0; j < 4; j++)
        acc[i][j] = __builtin_amdgcn_mfma_f32_16x16x32_bf16(a[i], b[j], acc[i][j], 0, 0, 0);
    if (it + 1 < niter) {
      *(ushort8*)(&As[nxt][ar * PK + ako]) = pa;
#pragma unroll
      for (int p = 0; p < 4; p++) {
        int i2 = tid + (p << 8);
        int br = i2 >> 2, bko = (i2 & 3) << 3;
        *(ushort8*)(&Bs[nxt][br * PK + bko]) = pb[p];
      }
    }
    __syncthreads();
  }

#pragma unroll
  for (int i = 0; i < 4; i++) {
#pragma unroll
    for (int j = 0; j < 4; j++) {
      int gc = (w << 6) + j * 16 + col16;
      int grb = row0 + i * 16 + quad * 4;
#pragma unroll
      for (int r = 0; r < 4; r++) {
        int gr = grb + r;
        if (gr < M) Cb[(size_t)gr * 256 + gc] = __float2bfloat16(acc[i][j][r]);
      }
    }
  }

  float ws4[4], wd4[4];
#pragma unroll
  for (int j = 0; j < 4; j++) {
    ws4[j] = att_s[(w << 6) + j * 16 + col16];
    wd4[j] = att_d[(w << 6) + j * 16 + col16];
  }
  float wavemax = -FLT_MAX;
#pragma unroll
  for (int i = 0; i < 4; i++) {
#pragma unroll
    for (int r = 0; r < 4; r++) {
      float vs = 0.f, vd = 0.f;
#pragma unroll
      for (int j = 0; j < 4; j++) {
        vs += acc[i][j][r] * ws4[j];
        vd += acc[i][j][r] * wd4[j];
      }
#pragma unroll
      for (int off = 1; off < 16; off <<= 1) {
        vs += __shfl_xor(vs, off);
        vd += __shfl_xor(vd, off);
      }
      int gr = row0 + i * 16 + quad * 4 + r;
      if (col16 == 0 && gr < M) {
        a_s[(size_t)gr * 4 + w] = vs;
        a_d[(size_t)gr * 4 + w] = vd;
      }
      wavemax = fmaxf(wavemax, vs);
    }
  }
  wavemax = fmaxf(wavemax, __shfl_xor(wavemax, 16));
  wavemax = fmaxf(wavemax, __shfl_xor(wavemax, 32));
  if (lane == 0) atomicMax(gmax_u + w, fkey(wavemax));
}

// ---------------------------------------------------------------------------
// Fused post_mp with dbuf stage 1 (R7 proven).
// ---------------------------------------------------------------------------
#define TS 72

__global__ void __launch_bounds__(256) postmp_fused(
    const __hip_bfloat16* __restrict__ A, const __hip_bfloat16* __restrict__ Wm1t,
    const __hip_bfloat16* __restrict__ Wm2t, const float* __restrict__ bm1,
    const float* __restrict__ bm2, float* __restrict__ out, int M) {
  __shared__ unsigned short smem[24576];
  unsigned short* W2s = &smem[15360];
  int tid = threadIdx.x;
  int lane = tid & 63, w = tid >> 6;
  int col16 = lane & 15, quad = lane >> 4;
  int row0 = blockIdx.x * 128;
  const unsigned short* Ag = (const unsigned short*)A;
  const unsigned short* Bg = (const unsigned short*)Wm1t;
  const unsigned short* W2g = (const unsigned short*)Wm2t;

#pragma unroll
  for (int c = tid; c < 1024; c += 256) {
    int r = c >> 3, ko = (c & 7) << 3;
    ushort8 v = {};
    if (r < 121) v = *(const ushort8*)(W2g + (size_t)r * 64 + ko);
    *(ushort8*)(&W2s[r * TS + ko]) = v;
  }

  int ar0 = tid >> 2, ako = (tid & 3) << 3;
  int agr0 = row0 + ar0;       if (agr0 >= M) agr0 = M - 1;
  int agr1 = row0 + ar0 + 64;  if (agr1 >= M) agr1 = M - 1;
  const unsigned short* aga0 = Ag + (size_t)agr0 * 256 + ako;
  const unsigned short* aga1 = Ag + (size_t)agr1 * 256 + ako;
  int br = tid >> 2, bko = (tid & 3) << 3;
  const unsigned short* bga = Bg + (size_t)br * 256 + bko;

  f32x4 acc1[2][4] = {};
  ushort8 pa0, pa1, pbv;
  pa0 = *(const ushort8*)(aga0);
  pa1 = *(const ushort8*)(aga1);
  pbv = *(const ushort8*)(bga);
  *(ushort8*)(&smem[ar0 * PK + ako]) = pa0;
  *(ushort8*)(&smem[(ar0 + 64) * PK + ako]) = pa1;
  *(ushort8*)(&smem[10240 + br * PK + bko]) = pbv;
  __syncthreads();

  for (int it = 0; it < 8; ++it) {
    int cur = it & 1, nxt = cur ^ 1;
    unsigned short* Asc = &smem[cur * 5120];
    unsigned short* Bsc = &smem[10240 + cur * 2560];
    int k1 = (it + 1) << 5;
    if (it + 1 < 8) {
      pa0 = *(const ushort8*)(aga0 + k1);
      pa1 = *(const ushort8*)(aga1 + k1);
      pbv = *(const ushort8*)(bga + k1);
    }
    bf16x8 a[2], b[4];
#pragma unroll
    for (int i = 0; i < 2; i++)
      a[i] = *(const bf16x8*)(&Asc[(w * 32 + i * 16 + col16) * PK + quad * 8]);
#pragma unroll
    for (int j = 0; j < 4; j++)
      b[j] = *(const bf16x8*)(&Bsc[(j * 16 + col16) * PK + quad * 8]);
#pragma unroll
    for (int i = 0; i < 2; i++)
#pragma unroll
      for (int j = 0; j < 4; j++)
        acc1[i][j] = __builtin_amdgcn_mfma_f32_16x16x32_bf16(a[i], b[j], acc1[i][j], 0, 0, 0);
    if (it + 1 < 8) {
      unsigned short* Asn = &smem[nxt * 5120];
      unsigned short* Bsn = &smem[10240 + nxt * 2560];
      *(ushort8*)(&Asn[ar0 * PK + ako]) = pa0;
      *(ushort8*)(&Asn[(ar0 + 64) * PK + ako]) = pa1;
      *(ushort8*)(&Bsn[br * PK + bko]) = pbv;
    }
    __syncthreads();
  }

  unsigned short* T = &smem[0];
#pragma unroll
  for (int i = 0; i < 2; i++) {
#pragma unroll
    for (int j = 0; j < 4; j++) {
      int col = j * 16 + col16;
      float bv = bm1[col];
#pragma unroll
      for (int r = 0; r < 4; r++) {
        int rl = w * 32 + i * 16 + quad * 4 + r;
        __hip_bfloat16 hv = __float2bfloat16(acc1[i][j][r] + bv);
        T[rl * TS + col] = *reinterpret_cast<unsigned short*>(&hv);
      }
    }
  }
  __syncthreads();

  int wm2 = w & 1, wn2 = w >> 1;
  f32x4 acc2[4][4] = {};
#pragma unroll
  for (int kk = 0; kk < 2; kk++) {
    bf16x8 a[4], b[4];
#pragma unroll
    for (int i = 0; i < 4; i++)
      a[i] = *(const bf16x8*)(&T[(wm2 * 64 + i * 16 + col16) * TS + kk * 32 + quad * 8]);
#pragma unroll
    for (int j = 0; j < 4; j++)
      b[j] = *(const bf16x8*)(&W2s[(wn2 * 64 + j * 16 + col16) * TS + kk * 32 + quad * 8]);
#pragma unroll
    for (int i = 0; i < 4; i++)
#pragma unroll
      for (int j = 0; j < 4; j++)
        acc2[i][j] = __builtin_amdgcn_mfma_f32_16x16x32_bf16(a[i], b[j], acc2[i][j], 0, 0, 0);
  }
#pragma unroll
  for (int i = 0; i < 4; i++) {
#pragma unroll
    for (int j = 0; j < 4; j++) {
      int gc = wn2 * 64 + j * 16 + col16;
      if (gc >= 121) continue;
      float bv = bm2[gc];
      int grb = row0 + wm2 * 64 + i * 16 + quad * 4;
#pragma unroll
      for (int r = 0; r < 4; r++) {
        int gr = grb + r;
        if (gr >= M) continue;
        float v = acc2[i][j][r] + bv;
        out[(size_t)gr * 121 + gc] = 1.f / (1.f + __expf(-v));
      }
    }
  }
}

// ---------------------------------------------------------------------------
// setup: x cast + all weight transposes + slot/cursor init + gmax_u zero.
// ---------------------------------------------------------------------------
__global__ void setup_all(const float* __restrict__ x, __hip_bfloat16* __restrict__ xb,
                          const float* __restrict__ W1, const float* __restrict__ W2,
                          const float* __restrict__ Wm1, const float* __restrict__ Wm2,
                          __hip_bfloat16* __restrict__ W1t, __hip_bfloat16* __restrict__ W2t,
                          __hip_bfloat16* __restrict__ Wm1t, __hip_bfloat16* __restrict__ Wm2t,
                          int* __restrict__ cur, int* __restrict__ slots,
                          unsigned* __restrict__ gmax_u,
                          int n, int castBlocks, int prepBlocks) {
  int b = blockIdx.x;
  int tid = threadIdx.x;
  if (b < castBlocks) {  // cast x -> xb (float4 -> bf16x4)
    int i = b * 256 + tid;
    if (i < n * 32) {
      float4 v = *(const float4*)(x + 4 * (size_t)i);
      uint2 pk;
      pk.x = packbf2(v.x, v.y);
      pk.y = packbf2(v.z, v.w);
      *(uint2*)((unsigned*)xb + 2 * (size_t)i) = pk;
    }
    return;
  }
  b -= castBlocks;
  if (b < prepBlocks) {  // weight transposes
    int i = b * 256 + tid;
    if (i < 128 * 256) {
      int nn = i / 128, kk = i - nn * 128;
      W1t[i] = __float2bfloat16(W1[(size_t)kk * 256 + nn]);
      return;
    }
    i -= 128 * 256;
    if (i < 256 * 256) {
      int nn = i / 256, kk = i - nn * 256;
      W2t[i] = __float2bfloat16(W2[(size_t)kk * 256 + nn]);
      return;
    }
    i -= 256 * 256;
    if (i < 256 * 64) {
      int nn = i / 256, kk = i - nn * 256;
      Wm1t[i] = __float2bfloat16(Wm1[(size_t)kk * 64 + nn]);
      return;
    }
    i -= 256 * 64;
    if (i < 64 * 121) {
      int nn = i / 64, kk = i - nn * 64;
      Wm2t[i] = __float2bfloat16(Wm2[(size_t)kk * 121 + nn]);
    }
    return;
  }
  b -= prepBlocks;
  {  // slot init: self-loop in slot 0, cursor = 1; block 0 zeroes gmax keys
    if (b == 0 && tid < 8) gmax_u[tid] = 0u;  // key 0 < every real key
    int i = b * 256 + tid;
    if (i < n) {
      cur[i] = 1;
      slots[(size_t)i << SLOG] = i;
    }
  }
}

// fill adjacency slots (dst-bucketed, unordered)
__global__ void slot_fill(const int* __restrict__ ei, int E,
                          int* __restrict__ cur, int* __restrict__ slots) {
  int i = blockIdx.x * 256 + threadIdx.x;
  if (i >= E) return;
  int s = ei[i], d = ei[E + i];
  int pos = atomicAdd(&cur[d], 1);
  slots[((size_t)d << SLOG) + pos] = s;
}

// ---------------------------------------------------------------------------
// GAT aggregation — R13: the R9 proven row-major body (64.5us/dispatch, at
// the ~60us L3-fabric floor: FETCH 209MB = 8 XCD x 26MB compulsory @3.5TB/s.
// R10 pipelining: -6% (latency not the limit). R12 slicing: -188% (8x wave
// overhead). Both reverted). Only change vs R9: gmax read decodes the
// atomicMax key written by the conv epilogue.
// ---------------------------------------------------------------------------
__global__ void __launch_bounds__(256) gat_aggregate(
    const __hip_bfloat16* __restrict__ hb, const float* __restrict__ a_src,
    const float* __restrict__ a_dst, const int* __restrict__ cnt_arr,
    const int* __restrict__ slots, const float* __restrict__ bias,
    const unsigned* __restrict__ gmax_u, int goff,
    __hip_bfloat16* __restrict__ out, int n) {
  __shared__ float plds[4][256];
  int wid = threadIdx.x >> 6;
  int lane = threadIdx.x & 63;
  int half = lane >> 5;
  int l32 = lane & 31;
  int qh = l32 >> 3;
  int node = (blockIdx.x << 2) + wid;
  if (node >= n) return;
  float4 adv = *(const float4*)(a_dst + (size_t)node * 4);
  float m0 = fdec(gmax_u[goff + 0]) + adv.x; m0 = fmaxf(m0, NEG_SLOPE * m0);
  float m1 = fdec(gmax_u[goff + 1]) + adv.y; m1 = fmaxf(m1, NEG_SLOPE * m1);
  float m2 = fdec(gmax_u[goff + 2]) + adv.z; m2 = fmaxf(m2, NEG_SLOPE * m2);
  float m3 = fdec(gmax_u[goff + 3]) + adv.w; m3 = fmaxf(m3, NEG_SLOPE * m3);
  int cntN = __builtin_amdgcn_readfirstlane(cnt_arr[node]);
  int beg = node << SLOG;
  const uint4* hw4 = (const uint4*)hb;

  float lq = 0.f;
  float c0 = 0.f, c1 = 0.f, c2 = 0.f, c3 = 0.f;
  float c4 = 0.f, c5 = 0.f, c6 = 0.f, c7 = 0.f;

  for (int cbeg = 0; cbeg < cntN; cbeg += 64) {
    int cnt = cntN - cbeg; if (cnt > 64) cnt = 64;
    int eidx = beg + cbeg + (lane < cnt ? lane : cnt - 1);
    int s_l = slots[eidx];
    float4 as = *(const float4*)(a_src + (size_t)s_l * 4);
    float v0 = as.x + adv.x; v0 = fmaxf(v0, NEG_SLOPE * v0);
    float v1 = as.y + adv.y; v1 = fmaxf(v1, NEG_SLOPE * v1);
    float v2 = as.z + adv.z; v2 = fmaxf(v2, NEG_SLOPE * v2);
    float v3 = as.w + adv.w; v3 = fmaxf(v3, NEG_SLOPE * v3);
    float p0 = __expf(v0 - m0), p1 = __expf(v1 - m1);
    float p2 = __expf(v2 - m2), p3 = __expf(v3 - m3);
    *(float4*)&plds[wid][lane * 4] = make_float4(p0, p1, p2, p3);
    __builtin_amdgcn_s_waitcnt(0);

    auto step = [&](int j) {
      int jj = j + half;
      bool dup = jj >= cnt;
      int jc = dup ? cnt - 1 : jj;
      int sj = __shfl(s_l, jc);
      float pq = plds[wid][jc * 4 + qh];
      if (dup) pq = 0.f;
      uint4 d = hw4[(size_t)sj * 32 + l32];
      c0 += pq * bflo(d.x); c1 += pq * bfhi(d.x);
      c2 += pq * bflo(d.y); c3 += pq * bfhi(d.y);
      c4 += pq * bflo(d.z); c5 += pq * bfhi(d.z);
      c6 += pq * bflo(d.w); c7 += pq * bfhi(d.w);
      lq += pq;
    };
    // fully-predicated unrolled loop (R9 proven): no rolled tail.
    for (int j = 0; j < cnt; j += 8) { step(j); step(j + 2); step(j + 4); step(j + 6); }
  }

  lq += __shfl_xor(lq, 32);
  c0 += __shfl_xor(c0, 32); c1 += __shfl_xor(c1, 32);
  c2 += __shfl_xor(c2, 32); c3 += __shfl_xor(c3, 32);
  c4 += __shfl_xor(c4, 32); c5 += __shfl_xor(c5, 32);
  c6 += __shfl_xor(c6, 32); c7 += __shfl_xor(c7, 32);

  if (half == 0) {
    float4 bA = *(const float4*)(bias + 8 * l32);
    float4 bB = *(const float4*)(bias + 8 * l32 + 4);
    float rq = 1.f / (lq + EPS);
    float o0 = fmaxf(c0 * rq + bA.x, 0.f);
    float o1 = fmaxf(c1 * rq + bA.y, 0.f);
    float o2 = fmaxf(c2 * rq + bA.z, 0.f);
    float o3 = fmaxf(c3 * rq + bA.w, 0.f);
    float o4 = fmaxf(c4 * rq + bB.x, 0.f);
    float o5 = fmaxf(c5 * rq + bB.y, 0.f);
    float o6 = fmaxf(c6 * rq + bB.z, 0.f);
    float o7 = fmaxf(c7 * rq + bB.w, 0.f);
    uint4 pk;
    pk.x = packbf2(o0, o1);
    pk.y = packbf2(o2, o3);
    pk.z = packbf2(o4, o5);
    pk.w = packbf2(o6, o7);
    *(uint4*)((unsigned*)out + (size_t)node * 128 + l32 * 4) = pk;
  }
}

// ---------------------------------------------------------------------------
extern "C" void kernel_launch(void* const* d_in, const int* in_sizes, int n_in,
                              void* d_out, int out_size, void* d_ws, size_t ws_size,
                              hipStream_t stream) {
  const float* x      = (const float*)d_in[0];
  const int*   ei     = (const int*)d_in[1];
  const float* W1     = (const float*)d_in[2];
  const float* att_s1 = (const float*)d_in[3];
  const float* att_d1 = (const float*)d_in[4];
  const float* b1     = (const float*)d_in[5];
  const float* W2     = (const float*)d_in[6];
  const float* att_s2 = (const float*)d_in[7];
  const float* att_d2 = (const float*)d_in[8];
  const float* b2     = (const float*)d_in[9];
  const float* Wm1    = (const float*)d_in[10];
  const float* bm1    = (const float*)d_in[11];
  const float* Wm2    = (const float*)d_in[12];
  const float* bm2    = (const float*)d_in[13];
  float* out = (float*)d_out;

  int n = in_sizes[0] / 128;   // 50000
  int E = in_sizes[1] / 2;     // 800000

  char* ws = (char*)d_ws;
  size_t off = 0;
  auto carve = [&](size_t bytes) {
    char* p = ws + off;
    off += (bytes + 255) & ~(size_t)255;
    return p;
  };
  __hip_bfloat16* hb   = (__hip_bfloat16*)carve((size_t)n * HC * 2);
  __hip_bfloat16* aggb = (__hip_bfloat16*)carve((size_t)n * HC * 2);
  __hip_bfloat16* xb   = (__hip_bfloat16*)carve((size_t)n * 128 * 2);
  __hip_bfloat16* W1t  = (__hip_bfloat16*)carve((size_t)128 * HC * 2);
  __hip_bfloat16* W2t  = (__hip_bfloat16*)carve((size_t)HC * HC * 2);
  __hip_bfloat16* Wm1t = (__hip_bfloat16*)carve((size_t)HC * HID * 2);
  __hip_bfloat16* Wm2t = (__hip_bfloat16*)carve((size_t)HID * 121 * 2);
  float* as    = (float*)carve((size_t)n * HEADS * 4);
  float* ad    = (float*)carve((size_t)n * HEADS * 4);
  int*   cur   = (int*)carve((size_t)n * 4);
  int*   slots = (int*)carve(((size_t)n << SLOG) * 4);
  unsigned* gmax_u = (unsigned*)carve((size_t)8 * 4);
  (void)ws_size;

  int rows64 = (n + 63) / 64;
  int castBlocks = (n * 32 + 255) / 256;            // 6250
  int prepBlocks = (122432 + 255) / 256;            // 479
  int slotBlocks = (n + 255) / 256;                 // 196

  // 1: setup (cast + transposes + slot init + gmax zero)
  setup_all<<<castBlocks + prepBlocks + slotBlocks, 256, 0, stream>>>(
      x, xb, W1, W2, Wm1, Wm2, W1t, W2t, Wm1t, Wm2t, cur, slots, gmax_u,
      n, castBlocks, prepBlocks);
  // 2: adjacency fill
  slot_fill<<<(E + 255) / 256, 256, 0, stream>>>(ei, E, cur, slots);

  // 3: conv1 (+ fused attn coefs + gmax atomics)
  conv_gemm_attn<<<rows64, 256, 0, stream>>>(
      xb, W1t, hb, att_s1, att_d1, as, ad, gmax_u + 0, n, 128);
  // 4: aggregate 1
  gat_aggregate<<<(n + 3) / 4, 256, 0, stream>>>(hb, as, ad, cur, slots, b1, gmax_u, 0, aggb, n);

  // 5: conv2
  conv_gemm_attn<<<rows64, 256, 0, stream>>>(
      aggb, W2t, hb, att_s2, att_d2, as, ad, gmax_u + 4, n, HC);
  // 6: aggregate 2
  gat_aggregate<<<(n + 3) / 4, 256, 0, stream>>>(hb, as, ad, cur, slots, b2, gmax_u, 4, aggb, n);

  // 7: post_mp
  postmp_fused<<<(n + 127) / 128, 256, 0, stream>>>(aggb, Wm1t, Wm2t, bm1, bm2, out, n);
}

// Round 10
// 377.329 us; speedup vs baseline: 1.5116x; 1.0773x over previous
//
#include <hip/hip_runtime.h>
#include <hip/hip_bf16.h>
#include <float.h>

#define HEADS 4
#define HID 64
#define HC 256   // HEADS*HID
#define NEG_SLOPE 0.2f
#define EPS 1e-16f
#define SLOG 7           // log2 slots per node
#define SLOTS 128        // fixed adjacency slots per node (max in-deg ~45)

typedef short bf16x8 __attribute__((ext_vector_type(8)));
typedef float f32x4 __attribute__((ext_vector_type(4)));
typedef unsigned short ushort8 __attribute__((ext_vector_type(8)));

__device__ __forceinline__ float bflo(unsigned u) { return __uint_as_float(u << 16); }
__device__ __forceinline__ float bfhi(unsigned u) { return __uint_as_float(u & 0xffff0000u); }
__device__ __forceinline__ unsigned packbf2(float a, float b) {
  __hip_bfloat16 ha = __float2bfloat16(a), hb = __float2bfloat16(b);
  unsigned short ua = *reinterpret_cast<unsigned short*>(&ha);
  unsigned short ub = *reinterpret_cast<unsigned short*>(&hb);
  return (unsigned)ua | ((unsigned)ub << 16);
}

#define PK 40  // padded LDS row stride (bf16 elems) — proven conflict-light

// ---------------------------------------------------------------------------
// Conv GEMM — R14: 128-row tile (m93 64->128 analog). R13's epilogue atomicMax
// cost +44us total (R8 lesson: global contention in epilogue > launch savings)
// -> reverted to blockmax store + reduce_gmax. Budget shows convs ~55-64us
// each (below top-5 cutoff), staging-bound; doubling rows/block doubles MFMA
// per staged B-byte. A-staging = postmp's proven two-half pattern.
// acc 8x4 (~215 VGPR), LDS 61KB -> 2 blocks/CU.
// ---------------------------------------------------------------------------
__global__ void __launch_bounds__(256) conv_gemm_attn(
    const __hip_bfloat16* __restrict__ A, const __hip_bfloat16* __restrict__ Bt,
    __hip_bfloat16* __restrict__ Cb,
    const float* __restrict__ att_s, const float* __restrict__ att_d,
    float* __restrict__ a_s, float* __restrict__ a_d,
    float* __restrict__ blockmax, int M, int K) {
  __shared__ unsigned short As[2][128 * PK];
  __shared__ unsigned short Bs[2][256 * PK];
  int tid = threadIdx.x;
  int lane = tid & 63, w = tid >> 6;
  int col16 = lane & 15, quad = lane >> 4;
  int row0 = blockIdx.x * 128;
  const unsigned short* Ag = (const unsigned short*)A;
  const unsigned short* Bg = (const unsigned short*)Bt;

  int ar = tid >> 2;           // 0..63
  int ako = (tid & 3) << 3;    // 0,8,16,24
  int agr0 = row0 + ar;      if (agr0 >= M) agr0 = M - 1;
  int agr1 = row0 + ar + 64; if (agr1 >= M) agr1 = M - 1;
  const unsigned short* aga0 = Ag + (size_t)agr0 * K + ako;
  const unsigned short* aga1 = Ag + (size_t)agr1 * K + ako;

  f32x4 acc[8][4] = {};
  int niter = K >> 5;

  ushort8 pa0, pa1, pb[4];
  pa0 = *(const ushort8*)(aga0);
  pa1 = *(const ushort8*)(aga1);
#pragma unroll
  for (int p = 0; p < 4; p++) {
    int i2 = tid + (p << 8);
    int br = i2 >> 2, bko = (i2 & 3) << 3;
    pb[p] = *(const ushort8*)(Bg + (size_t)br * K + bko);
  }
  *(ushort8*)(&As[0][ar * PK + ako]) = pa0;
  *(ushort8*)(&As[0][(ar + 64) * PK + ako]) = pa1;
#pragma unroll
  for (int p = 0; p < 4; p++) {
    int i2 = tid + (p << 8);
    int br = i2 >> 2, bko = (i2 & 3) << 3;
    *(ushort8*)(&Bs[0][br * PK + bko]) = pb[p];
  }
  __syncthreads();

  for (int it = 0; it < niter; ++it) {
    int cur = it & 1, nxt = cur ^ 1;
    int k1 = (it + 1) << 5;
    if (it + 1 < niter) {
      pa0 = *(const ushort8*)(aga0 + k1);
      pa1 = *(const ushort8*)(aga1 + k1);
#pragma unroll
      for (int p = 0; p < 4; p++) {
        int i2 = tid + (p << 8);
        int br = i2 >> 2, bko = (i2 & 3) << 3;
        pb[p] = *(const ushort8*)(Bg + (size_t)br * K + k1 + bko);
      }
    }
    bf16x8 a[8], b[4];
#pragma unroll
    for (int i = 0; i < 8; i++)
      a[i] = *(const bf16x8*)(&As[cur][(i * 16 + col16) * PK + quad * 8]);
#pragma unroll
    for (int j = 0; j < 4; j++)
      b[j] = *(const bf16x8*)(&Bs[cur][((w << 6) + j * 16 + col16) * PK + quad * 8]);
#pragma unroll
    for (int i = 0; i < 8; i++)
#pragma unroll
      for (int j = 0; j < 4; j++)
        acc[i][j] = __builtin_amdgcn_mfma_f32_16x16x32_bf16(a[i], b[j], acc[i][j], 0, 0, 0);
    if (it + 1 < niter) {
      *(ushort8*)(&As[nxt][ar * PK + ako]) = pa0;
      *(ushort8*)(&As[nxt][(ar + 64) * PK + ako]) = pa1;
#pragma unroll
      for (int p = 0; p < 4; p++) {
        int i2 = tid + (p << 8);
        int br = i2 >> 2, bko = (i2 & 3) << 3;
        *(ushort8*)(&Bs[nxt][br * PK + bko]) = pb[p];
      }
    }
    __syncthreads();
  }

#pragma unroll
  for (int i = 0; i < 8; i++) {
#pragma unroll
    for (int j = 0; j < 4; j++) {
      int gc = (w << 6) + j * 16 + col16;
      int grb = row0 + i * 16 + quad * 4;
#pragma unroll
      for (int r = 0; r < 4; r++) {
        int gr = grb + r;
        if (gr < M) Cb[(size_t)gr * 256 + gc] = __float2bfloat16(acc[i][j][r]);
      }
    }
  }

  float ws4[4], wd4[4];
#pragma unroll
  for (int j = 0; j < 4; j++) {
    ws4[j] = att_s[(w << 6) + j * 16 + col16];
    wd4[j] = att_d[(w << 6) + j * 16 + col16];
  }
  float wavemax = -FLT_MAX;
#pragma unroll
  for (int i = 0; i < 8; i++) {
#pragma unroll
    for (int r = 0; r < 4; r++) {
      float vs = 0.f, vd = 0.f;
#pragma unroll
      for (int j = 0; j < 4; j++) {
        vs += acc[i][j][r] * ws4[j];
        vd += acc[i][j][r] * wd4[j];
      }
#pragma unroll
      for (int off = 1; off < 16; off <<= 1) {
        vs += __shfl_xor(vs, off);
        vd += __shfl_xor(vd, off);
      }
      int gr = row0 + i * 16 + quad * 4 + r;
      if (col16 == 0 && gr < M) {
        a_s[(size_t)gr * 4 + w] = vs;
        a_d[(size_t)gr * 4 + w] = vd;
      }
      wavemax = fmaxf(wavemax, vs);
    }
  }
  wavemax = fmaxf(wavemax, __shfl_xor(wavemax, 16));
  wavemax = fmaxf(wavemax, __shfl_xor(wavemax, 32));
  if (lane == 0) blockmax[(size_t)blockIdx.x * 4 + w] = wavemax;
}

// reduce blockmax[nb][4] -> gmaxf[goff+0..3]  (~2us, no fence in hot kernel;
// R13's atomicMax fusion cost +44us — this stays a separate dispatch)
__global__ void __launch_bounds__(256) reduce_gmax(const float* __restrict__ blockmax,
                                                   float* __restrict__ gmaxf, int goff, int nb) {
  __shared__ float wm[4][4];
  int tid = threadIdx.x, lane = tid & 63, w = tid >> 6;
  int hd = tid & 3;
  float m = -FLT_MAX;
  for (int i = tid >> 2; i < nb; i += 64)
    m = fmaxf(m, blockmax[(size_t)i * 4 + hd]);
#pragma unroll
  for (int off = 4; off < 64; off <<= 1)
    m = fmaxf(m, __shfl_xor(m, off));
  if (lane < 4) wm[w][lane] = m;
  __syncthreads();
  if (tid < 4) {
    float r = fmaxf(fmaxf(wm[0][tid], wm[1][tid]), fmaxf(wm[2][tid], wm[3][tid]));
    gmaxf[goff + tid] = r;
  }
}

// ---------------------------------------------------------------------------
// Fused post_mp with dbuf stage 1 (R7 proven).
// ---------------------------------------------------------------------------
#define TS 72

__global__ void __launch_bounds__(256) postmp_fused(
    const __hip_bfloat16* __restrict__ A, const __hip_bfloat16* __restrict__ Wm1t,
    const __hip_bfloat16* __restrict__ Wm2t, const float* __restrict__ bm1,
    const float* __restrict__ bm2, float* __restrict__ out, int M) {
  __shared__ unsigned short smem[24576];
  unsigned short* W2s = &smem[15360];
  int tid = threadIdx.x;
  int lane = tid & 63, w = tid >> 6;
  int col16 = lane & 15, quad = lane >> 4;
  int row0 = blockIdx.x * 128;
  const unsigned short* Ag = (const unsigned short*)A;
  const unsigned short* Bg = (const unsigned short*)Wm1t;
  const unsigned short* W2g = (const unsigned short*)Wm2t;

#pragma unroll
  for (int c = tid; c < 1024; c += 256) {
    int r = c >> 3, ko = (c & 7) << 3;
    ushort8 v = {};
    if (r < 121) v = *(const ushort8*)(W2g + (size_t)r * 64 + ko);
    *(ushort8*)(&W2s[r * TS + ko]) = v;
  }

  int ar0 = tid >> 2, ako = (tid & 3) << 3;
  int agr0 = row0 + ar0;       if (agr0 >= M) agr0 = M - 1;
  int agr1 = row0 + ar0 + 64;  if (agr1 >= M) agr1 = M - 1;
  const unsigned short* aga0 = Ag + (size_t)agr0 * 256 + ako;
  const unsigned short* aga1 = Ag + (size_t)agr1 * 256 + ako;
  int br = tid >> 2, bko = (tid & 3) << 3;
  const unsigned short* bga = Bg + (size_t)br * 256 + bko;

  f32x4 acc1[2][4] = {};
  ushort8 pa0, pa1, pbv;
  pa0 = *(const ushort8*)(aga0);
  pa1 = *(const ushort8*)(aga1);
  pbv = *(const ushort8*)(bga);
  *(ushort8*)(&smem[ar0 * PK + ako]) = pa0;
  *(ushort8*)(&smem[(ar0 + 64) * PK + ako]) = pa1;
  *(ushort8*)(&smem[10240 + br * PK + bko]) = pbv;
  __syncthreads();

  for (int it = 0; it < 8; ++it) {
    int cur = it & 1, nxt = cur ^ 1;
    unsigned short* Asc = &smem[cur * 5120];
    unsigned short* Bsc = &smem[10240 + cur * 2560];
    int k1 = (it + 1) << 5;
    if (it + 1 < 8) {
      pa0 = *(const ushort8*)(aga0 + k1);
      pa1 = *(const ushort8*)(aga1 + k1);
      pbv = *(const ushort8*)(bga + k1);
    }
    bf16x8 a[2], b[4];
#pragma unroll
    for (int i = 0; i < 2; i++)
      a[i] = *(const bf16x8*)(&Asc[(w * 32 + i * 16 + col16) * PK + quad * 8]);
#pragma unroll
    for (int j = 0; j < 4; j++)
      b[j] = *(const bf16x8*)(&Bsc[(j * 16 + col16) * PK + quad * 8]);
#pragma unroll
    for (int i = 0; i < 2; i++)
#pragma unroll
      for (int j = 0; j < 4; j++)
        acc1[i][j] = __builtin_amdgcn_mfma_f32_16x16x32_bf16(a[i], b[j], acc1[i][j], 0, 0, 0);
    if (it + 1 < 8) {
      unsigned short* Asn = &smem[nxt * 5120];
      unsigned short* Bsn = &smem[10240 + nxt * 2560];
      *(ushort8*)(&Asn[ar0 * PK + ako]) = pa0;
      *(ushort8*)(&Asn[(ar0 + 64) * PK + ako]) = pa1;
      *(ushort8*)(&Bsn[br * PK + bko]) = pbv;
    }
    __syncthreads();
  }

  unsigned short* T = &smem[0];
#pragma unroll
  for (int i = 0; i < 2; i++) {
#pragma unroll
    for (int j = 0; j < 4; j++) {
      int col = j * 16 + col16;
      float bv = bm1[col];
#pragma unroll
      for (int r = 0; r < 4; r++) {
        int rl = w * 32 + i * 16 + quad * 4 + r;
        __hip_bfloat16 hv = __float2bfloat16(acc1[i][j][r] + bv);
        T[rl * TS + col] = *reinterpret_cast<unsigned short*>(&hv);
      }
    }
  }
  __syncthreads();

  int wm2 = w & 1, wn2 = w >> 1;
  f32x4 acc2[4][4] = {};
#pragma unroll
  for (int kk = 0; kk < 2; kk++) {
    bf16x8 a[4], b[4];
#pragma unroll
    for (int i = 0; i < 4; i++)
      a[i] = *(const bf16x8*)(&T[(wm2 * 64 + i * 16 + col16) * TS + kk * 32 + quad * 8]);
#pragma unroll
    for (int j = 0; j < 4; j++)
      b[j] = *(const bf16x8*)(&W2s[(wn2 * 64 + j * 16 + col16) * TS + kk * 32 + quad * 8]);
#pragma unroll
    for (int i = 0; i < 4; i++)
#pragma unroll
      for (int j = 0; j < 4; j++)
        acc2[i][j] = __builtin_amdgcn_mfma_f32_16x16x32_bf16(a[i], b[j], acc2[i][j], 0, 0, 0);
  }
#pragma unroll
  for (int i = 0; i < 4; i++) {
#pragma unroll
    for (int j = 0; j < 4; j++) {
      int gc = wn2 * 64 + j * 16 + col16;
      if (gc >= 121) continue;
      float bv = bm2[gc];
      int grb = row0 + wm2 * 64 + i * 16 + quad * 4;
#pragma unroll
      for (int r = 0; r < 4; r++) {
        int gr = grb + r;
        if (gr >= M) continue;
        float v = acc2[i][j][r] + bv;
        out[(size_t)gr * 121 + gc] = 1.f / (1.f + __expf(-v));
      }
    }
  }
}

// ---------------------------------------------------------------------------
// setup: x cast + all weight transposes + slot/cursor init, one kernel.
// ---------------------------------------------------------------------------
__global__ void setup_all(const float* __restrict__ x, __hip_bfloat16* __restrict__ xb,
                          const float* __restrict__ W1, const float* __restrict__ W2,
                          const float* __restrict__ Wm1, const float* __restrict__ Wm2,
                          __hip_bfloat16* __restrict__ W1t, __hip_bfloat16* __restrict__ W2t,
                          __hip_bfloat16* __restrict__ Wm1t, __hip_bfloat16* __restrict__ Wm2t,
                          int* __restrict__ cur, int* __restrict__ slots,
                          int n, int castBlocks, int prepBlocks) {
  int b = blockIdx.x;
  int tid = threadIdx.x;
  if (b < castBlocks) {  // cast x -> xb (float4 -> bf16x4)
    int i = b * 256 + tid;
    if (i < n * 32) {
      float4 v = *(const float4*)(x + 4 * (size_t)i);
      uint2 pk;
      pk.x = packbf2(v.x, v.y);
      pk.y = packbf2(v.z, v.w);
      *(uint2*)((unsigned*)xb + 2 * (size_t)i) = pk;
    }
    return;
  }
  b -= castBlocks;
  if (b < prepBlocks) {  // weight transposes
    int i = b * 256 + tid;
    if (i < 128 * 256) {
      int nn = i / 128, kk = i - nn * 128;
      W1t[i] = __float2bfloat16(W1[(size_t)kk * 256 + nn]);
      return;
    }
    i -= 128 * 256;
    if (i < 256 * 256) {
      int nn = i / 256, kk = i - nn * 256;
      W2t[i] = __float2bfloat16(W2[(size_t)kk * 256 + nn]);
      return;
    }
    i -= 256 * 256;
    if (i < 256 * 64) {
      int nn = i / 256, kk = i - nn * 256;
      Wm1t[i] = __float2bfloat16(Wm1[(size_t)kk * 64 + nn]);
      return;
    }
    i -= 256 * 64;
    if (i < 64 * 121) {
      int nn = i / 64, kk = i - nn * 64;
      Wm2t[i] = __float2bfloat16(Wm2[(size_t)kk * 121 + nn]);
    }
    return;
  }
  b -= prepBlocks;
  {  // slot init: self-loop in slot 0, cursor = 1
    int i = b * 256 + tid;
    if (i < n) {
      cur[i] = 1;
      slots[(size_t)i << SLOG] = i;
    }
  }
}

// fill adjacency slots (dst-bucketed, unordered)
__global__ void slot_fill(const int* __restrict__ ei, int E,
                          int* __restrict__ cur, int* __restrict__ slots) {
  int i = blockIdx.x * 256 + threadIdx.x;
  if (i >= E) return;
  int s = ei[i], d = ei[E + i];
  int pos = atomicAdd(&cur[d], 1);
  slots[((size_t)d << SLOG) + pos] = s;
}

// ---------------------------------------------------------------------------
// GAT aggregation — R9 proven body, unchanged (64.5us/dispatch, at the ~60us
// L3-fabric floor: FETCH 209MB = 8 XCD x 26MB compulsory @3.5TB/s. R10
// pipelining -6%, R12 slicing -188%, R13 atomic-gmax -44us total: all
// reverted).
// ---------------------------------------------------------------------------
__global__ void __launch_bounds__(256) gat_aggregate(
    const __hip_bfloat16* __restrict__ hb, const float* __restrict__ a_src,
    const float* __restrict__ a_dst, const int* __restrict__ cnt_arr,
    const int* __restrict__ slots, const float* __restrict__ bias,
    const float* __restrict__ gmaxf, int goff,
    __hip_bfloat16* __restrict__ out, int n) {
  __shared__ float plds[4][256];
  int wid = threadIdx.x >> 6;
  int lane = threadIdx.x & 63;
  int half = lane >> 5;
  int l32 = lane & 31;
  int qh = l32 >> 3;
  int node = (blockIdx.x << 2) + wid;
  if (node >= n) return;
  float4 adv = *(const float4*)(a_dst + (size_t)node * 4);
  float m0 = gmaxf[goff + 0] + adv.x; m0 = fmaxf(m0, NEG_SLOPE * m0);
  float m1 = gmaxf[goff + 1] + adv.y; m1 = fmaxf(m1, NEG_SLOPE * m1);
  float m2 = gmaxf[goff + 2] + adv.z; m2 = fmaxf(m2, NEG_SLOPE * m2);
  float m3 = gmaxf[goff + 3] + adv.w; m3 = fmaxf(m3, NEG_SLOPE * m3);
  int cntN = __builtin_amdgcn_readfirstlane(cnt_arr[node]);
  int beg = node << SLOG;
  const uint4* hw4 = (const uint4*)hb;

  float lq = 0.f;
  float c0 = 0.f, c1 = 0.f, c2 = 0.f, c3 = 0.f;
  float c4 = 0.f, c5 = 0.f, c6 = 0.f, c7 = 0.f;

  for (int cbeg = 0; cbeg < cntN; cbeg += 64) {
    int cnt = cntN - cbeg; if (cnt > 64) cnt = 64;
    int eidx = beg + cbeg + (lane < cnt ? lane : cnt - 1);
    int s_l = slots[eidx];
    float4 as = *(const float4*)(a_src + (size_t)s_l * 4);
    float v0 = as.x + adv.x; v0 = fmaxf(v0, NEG_SLOPE * v0);
    float v1 = as.y + adv.y; v1 = fmaxf(v1, NEG_SLOPE * v1);
    float v2 = as.z + adv.z; v2 = fmaxf(v2, NEG_SLOPE * v2);
    float v3 = as.w + adv.w; v3 = fmaxf(v3, NEG_SLOPE * v3);
    float p0 = __expf(v0 - m0), p1 = __expf(v1 - m1);
    float p2 = __expf(v2 - m2), p3 = __expf(v3 - m3);
    *(float4*)&plds[wid][lane * 4] = make_float4(p0, p1, p2, p3);
    __builtin_amdgcn_s_waitcnt(0);

    auto step = [&](int j) {
      int jj = j + half;
      bool dup = jj >= cnt;
      int jc = dup ? cnt - 1 : jj;
      int sj = __shfl(s_l, jc);
      float pq = plds[wid][jc * 4 + qh];
      if (dup) pq = 0.f;
      uint4 d = hw4[(size_t)sj * 32 + l32];
      c0 += pq * bflo(d.x); c1 += pq * bfhi(d.x);
      c2 += pq * bflo(d.y); c3 += pq * bfhi(d.y);
      c4 += pq * bflo(d.z); c5 += pq * bfhi(d.z);
      c6 += pq * bflo(d.w); c7 += pq * bfhi(d.w);
      lq += pq;
    };
    // fully-predicated unrolled loop (R9 proven): no rolled tail.
    for (int j = 0; j < cnt; j += 8) { step(j); step(j + 2); step(j + 4); step(j + 6); }
  }

  lq += __shfl_xor(lq, 32);
  c0 += __shfl_xor(c0, 32); c1 += __shfl_xor(c1, 32);
  c2 += __shfl_xor(c2, 32); c3 += __shfl_xor(c3, 32);
  c4 += __shfl_xor(c4, 32); c5 += __shfl_xor(c5, 32);
  c6 += __shfl_xor(c6, 32); c7 += __shfl_xor(c7, 32);

  if (half == 0) {
    float4 bA = *(const float4*)(bias + 8 * l32);
    float4 bB = *(const float4*)(bias + 8 * l32 + 4);
    float rq = 1.f / (lq + EPS);
    float o0 = fmaxf(c0 * rq + bA.x, 0.f);
    float o1 = fmaxf(c1 * rq + bA.y, 0.f);
    float o2 = fmaxf(c2 * rq + bA.z, 0.f);
    float o3 = fmaxf(c3 * rq + bA.w, 0.f);
    float o4 = fmaxf(c4 * rq + bB.x, 0.f);
    float o5 = fmaxf(c5 * rq + bB.y, 0.f);
    float o6 = fmaxf(c6 * rq + bB.z, 0.f);
    float o7 = fmaxf(c7 * rq + bB.w, 0.f);
    uint4 pk;
    pk.x = packbf2(o0, o1);
    pk.y = packbf2(o2, o3);
    pk.z = packbf2(o4, o5);
    pk.w = packbf2(o6, o7);
    *(uint4*)((unsigned*)out + (size_t)node * 128 + l32 * 4) = pk;
  }
}

// ---------------------------------------------------------------------------
extern "C" void kernel_launch(void* const* d_in, const int* in_sizes, int n_in,
                              void* d_out, int out_size, void* d_ws, size_t ws_size,
                              hipStream_t stream) {
  const float* x      = (const float*)d_in[0];
  const int*   ei     = (const int*)d_in[1];
  const float* W1     = (const float*)d_in[2];
  const float* att_s1 = (const float*)d_in[3];
  const float* att_d1 = (const float*)d_in[4];
  const float* b1     = (const float*)d_in[5];
  const float* W2     = (const float*)d_in[6];
  const float* att_s2 = (const float*)d_in[7];
  const float* att_d2 = (const float*)d_in[8];
  const float* b2     = (const float*)d_in[9];
  const float* Wm1    = (const float*)d_in[10];
  const float* bm1    = (const float*)d_in[11];
  const float* Wm2    = (const float*)d_in[12];
  const float* bm2    = (const float*)d_in[13];
  float* out = (float*)d_out;

  int n = in_sizes[0] / 128;   // 50000
  int E = in_sizes[1] / 2;     // 800000

  char* ws = (char*)d_ws;
  size_t off = 0;
  auto carve = [&](size_t bytes) {
    char* p = ws + off;
    off += (bytes + 255) & ~(size_t)255;
    return p;
  };
  __hip_bfloat16* hb   = (__hip_bfloat16*)carve((size_t)n * HC * 2);
  __hip_bfloat16* aggb = (__hip_bfloat16*)carve((size_t)n * HC * 2);
  __hip_bfloat16* xb   = (__hip_bfloat16*)carve((size_t)n * 128 * 2);
  __hip_bfloat16* W1t  = (__hip_bfloat16*)carve((size_t)128 * HC * 2);
  __hip_bfloat16* W2t  = (__hip_bfloat16*)carve((size_t)HC * HC * 2);
  __hip_bfloat16* Wm1t = (__hip_bfloat16*)carve((size_t)HC * HID * 2);
  __hip_bfloat16* Wm2t = (__hip_bfloat16*)carve((size_t)HID * 121 * 2);
  float* as    = (float*)carve((size_t)n * HEADS * 4);
  float* ad    = (float*)carve((size_t)n * HEADS * 4);
  int*   cur   = (int*)carve((size_t)n * 4);
  int*   slots = (int*)carve(((size_t)n << SLOG) * 4);
  float* blockmax = (float*)carve((size_t)((n + 63) / 64) * 4 * 4);
  float* gmaxf    = (float*)carve((size_t)8 * 4);
  (void)ws_size;

  int rows128 = (n + 127) / 128;                    // 391 conv blocks
  int castBlocks = (n * 32 + 255) / 256;            // 6250
  int prepBlocks = (122432 + 255) / 256;            // 479
  int slotBlocks = (n + 255) / 256;                 // 196

  // 1: setup (cast + transposes + slot init)
  setup_all<<<castBlocks + prepBlocks + slotBlocks, 256, 0, stream>>>(
      x, xb, W1, W2, Wm1, Wm2, W1t, W2t, Wm1t, Wm2t, cur, slots,
      n, castBlocks, prepBlocks);
  // 2: adjacency fill
  slot_fill<<<(E + 255) / 256, 256, 0, stream>>>(ei, E, cur, slots);

  // 3: conv1 (+ fused attn coefs), 128-row tiles
  conv_gemm_attn<<<rows128, 256, 0, stream>>>(
      xb, W1t, hb, att_s1, att_d1, as, ad, blockmax, n, 128);
  // 4: gmax reduce
  reduce_gmax<<<1, 256, 0, stream>>>(blockmax, gmaxf, 0, rows128);
  // 5: aggregate 1
  gat_aggregate<<<(n + 3) / 4, 256, 0, stream>>>(hb, as, ad, cur, slots, b1, gmaxf, 0, aggb, n);

  // 6: conv2
  conv_gemm_attn<<<rows128, 256, 0, stream>>>(
      aggb, W2t, hb, att_s2, att_d2, as, ad, blockmax, n, HC);
  // 7: gmax reduce
  reduce_gmax<<<1, 256, 0, stream>>>(blockmax, gmaxf, 4, rows128);
  // 8: aggregate 2
  gat_aggregate<<<(n + 3) / 4, 256, 0, stream>>>(hb, as, ad, cur, slots, b2, gmaxf, 4, aggb, n);

  // 9: post_mp
  postmp_fused<<<(n + 127) / 128, 256, 0, stream>>>(aggb, Wm1t, Wm2t, bm1, bm2, out, n);
}

// Round 11
// 357.388 us; speedup vs baseline: 1.5960x; 1.0558x over previous
//
#include <hip/hip_runtime.h>
#include <hip/hip_bf16.h>
#include <float.h>

#define HEADS 4
#define HID 64
#define HC 256   // HEADS*HID
#define NEG_SLOPE 0.2f
#define EPS 1e-16f
#define SLOG 7           // log2 slots per node
#define SLOTS 128        // fixed adjacency slots per node (max in-deg ~45)

typedef short bf16x8 __attribute__((ext_vector_type(8)));
typedef float f32x4 __attribute__((ext_vector_type(4)));
typedef unsigned short ushort8 __attribute__((ext_vector_type(8)));

__device__ __forceinline__ float bflo(unsigned u) { return __uint_as_float(u << 16); }
__device__ __forceinline__ float bfhi(unsigned u) { return __uint_as_float(u & 0xffff0000u); }
__device__ __forceinline__ unsigned packbf2(float a, float b) {
  __hip_bfloat16 ha = __float2bfloat16(a), hb = __float2bfloat16(b);
  unsigned short ua = *reinterpret_cast<unsigned short*>(&ha);
  unsigned short ub = *reinterpret_cast<unsigned short*>(&hb);
  return (unsigned)ua | ((unsigned)ub << 16);
}

#define PK 40  // padded LDS row stride (bf16 elems) — proven conflict-light

// ---------------------------------------------------------------------------
// Conv GEMM — R15: 512-thread blocks, SAME 64x256 tile / 51KB LDS.
// History: R14's 128-row tile dropped waves/CU 12->8 and cost +7.4us/conv
// (latency/occupancy-bound, not staging-bound). R15 inverts the lever:
// 8 waves/block, wave w owns rows (w>>2)*32 x cols (w&3)*64; acc[2][4]
// (~90 VGPR) -> 5-6 waves/SIMD -> 16-24 waves/CU vs R9's 12. Row-split
// keeps head==one-wave so attn epilogue needs no cross-wave dot combine;
// wavemax merges wave pairs via 8-float LDS (no global atomics — R13).
// ---------------------------------------------------------------------------
__global__ void __launch_bounds__(512) conv_gemm_attn(
    const __hip_bfloat16* __restrict__ A, const __hip_bfloat16* __restrict__ Bt,
    __hip_bfloat16* __restrict__ Cb,
    const float* __restrict__ att_s, const float* __restrict__ att_d,
    float* __restrict__ a_s, float* __restrict__ a_d,
    float* __restrict__ blockmax, int M, int K) {
  __shared__ unsigned short As[2][64 * PK];
  __shared__ unsigned short Bs[2][256 * PK];
  int tid = threadIdx.x;
  int lane = tid & 63, w = tid >> 6;        // w: 0..7
  int col16 = lane & 15, quad = lane >> 4;
  int r0 = (w >> 2) * 32;                   // row half: 0 or 32
  int c0 = (w & 3) * 64;                    // head * 64
  int row0 = blockIdx.x * 64;
  const unsigned short* Ag = (const unsigned short*)A;
  const unsigned short* Bg = (const unsigned short*)Bt;

  bool doA = tid < 256;
  int ar = (tid & 255) >> 2;                // 0..63
  int ako = (tid & 3) << 3;                 // 0,8,16,24
  int agr = row0 + ar; if (agr >= M) agr = M - 1;
  const unsigned short* aga = Ag + (size_t)agr * K + ako;

  f32x4 acc[2][4] = {};
  int niter = K >> 5;

  ushort8 pa, pb[2];
  if (doA) pa = *(const ushort8*)(aga);
#pragma unroll
  for (int p = 0; p < 2; p++) {
    int i2 = tid + (p << 9);
    int br = i2 >> 2, bko = (i2 & 3) << 3;
    pb[p] = *(const ushort8*)(Bg + (size_t)br * K + bko);
  }
  if (doA) *(ushort8*)(&As[0][ar * PK + ako]) = pa;
#pragma unroll
  for (int p = 0; p < 2; p++) {
    int i2 = tid + (p << 9);
    int br = i2 >> 2, bko = (i2 & 3) << 3;
    *(ushort8*)(&Bs[0][br * PK + bko]) = pb[p];
  }
  __syncthreads();

  for (int it = 0; it < niter; ++it) {
    int cur = it & 1, nxt = cur ^ 1;
    int k1 = (it + 1) << 5;
    if (it + 1 < niter) {
      if (doA) pa = *(const ushort8*)(aga + k1);
#pragma unroll
      for (int p = 0; p < 2; p++) {
        int i2 = tid + (p << 9);
        int br = i2 >> 2, bko = (i2 & 3) << 3;
        pb[p] = *(const ushort8*)(Bg + (size_t)br * K + k1 + bko);
      }
    }
    bf16x8 a[2], b[4];
#pragma unroll
    for (int i = 0; i < 2; i++)
      a[i] = *(const bf16x8*)(&As[cur][(r0 + i * 16 + col16) * PK + quad * 8]);
#pragma unroll
    for (int j = 0; j < 4; j++)
      b[j] = *(const bf16x8*)(&Bs[cur][(c0 + j * 16 + col16) * PK + quad * 8]);
#pragma unroll
    for (int i = 0; i < 2; i++)
#pragma unroll
      for (int j = 0; j < 4; j++)
        acc[i][j] = __builtin_amdgcn_mfma_f32_16x16x32_bf16(a[i], b[j], acc[i][j], 0, 0, 0);
    if (it + 1 < niter) {
      if (doA) *(ushort8*)(&As[nxt][ar * PK + ako]) = pa;
#pragma unroll
      for (int p = 0; p < 2; p++) {
        int i2 = tid + (p << 9);
        int br = i2 >> 2, bko = (i2 & 3) << 3;
        *(ushort8*)(&Bs[nxt][br * PK + bko]) = pb[p];
      }
    }
    __syncthreads();
  }

#pragma unroll
  for (int i = 0; i < 2; i++) {
#pragma unroll
    for (int j = 0; j < 4; j++) {
      int gc = c0 + j * 16 + col16;
      int grb = row0 + r0 + i * 16 + quad * 4;
#pragma unroll
      for (int r = 0; r < 4; r++) {
        int gr = grb + r;
        if (gr < M) Cb[(size_t)gr * 256 + gc] = __float2bfloat16(acc[i][j][r]);
      }
    }
  }

  float ws4[4], wd4[4];
#pragma unroll
  for (int j = 0; j < 4; j++) {
    ws4[j] = att_s[c0 + j * 16 + col16];
    wd4[j] = att_d[c0 + j * 16 + col16];
  }
  float wavemax = -FLT_MAX;
#pragma unroll
  for (int i = 0; i < 2; i++) {
#pragma unroll
    for (int r = 0; r < 4; r++) {
      float vs = 0.f, vd = 0.f;
#pragma unroll
      for (int j = 0; j < 4; j++) {
        vs += acc[i][j][r] * ws4[j];
        vd += acc[i][j][r] * wd4[j];
      }
#pragma unroll
      for (int off = 1; off < 16; off <<= 1) {
        vs += __shfl_xor(vs, off);
        vd += __shfl_xor(vd, off);
      }
      int gr = row0 + r0 + i * 16 + quad * 4 + r;
      if (col16 == 0 && gr < M) {
        a_s[(size_t)gr * 4 + (w & 3)] = vs;
        a_d[(size_t)gr * 4 + (w & 3)] = vd;
      }
      wavemax = fmaxf(wavemax, vs);
    }
  }
  wavemax = fmaxf(wavemax, __shfl_xor(wavemax, 16));
  wavemax = fmaxf(wavemax, __shfl_xor(wavemax, 32));
  // merge wave pairs (w, w+4) through LDS (As is dead after last barrier)
  float* wmx = (float*)&As[0][0];
  if (lane == 0) wmx[w] = wavemax;
  __syncthreads();
  if (w < 4 && lane == 0)
    blockmax[(size_t)blockIdx.x * 4 + w] = fmaxf(wmx[w], wmx[w + 4]);
}

// reduce blockmax[nb][4] -> gmaxf[goff+0..3]  (~2us, no fence in hot kernel;
// R13's atomicMax fusion cost +44us — this stays a separate dispatch)
__global__ void __launch_bounds__(256) reduce_gmax(const float* __restrict__ blockmax,
                                                   float* __restrict__ gmaxf, int goff, int nb) {
  __shared__ float wm[4][4];
  int tid = threadIdx.x, lane = tid & 63, w = tid >> 6;
  int hd = tid & 3;
  float m = -FLT_MAX;
  for (int i = tid >> 2; i < nb; i += 64)
    m = fmaxf(m, blockmax[(size_t)i * 4 + hd]);
#pragma unroll
  for (int off = 4; off < 64; off <<= 1)
    m = fmaxf(m, __shfl_xor(m, off));
  if (lane < 4) wm[w][lane] = m;
  __syncthreads();
  if (tid < 4) {
    float r = fmaxf(fmaxf(wm[0][tid], wm[1][tid]), fmaxf(wm[2][tid], wm[3][tid]));
    gmaxf[goff + tid] = r;
  }
}

// ---------------------------------------------------------------------------
// Fused post_mp with dbuf stage 1 (R7 proven).
// ---------------------------------------------------------------------------
#define TS 72

__global__ void __launch_bounds__(256) postmp_fused(
    const __hip_bfloat16* __restrict__ A, const __hip_bfloat16* __restrict__ Wm1t,
    const __hip_bfloat16* __restrict__ Wm2t, const float* __restrict__ bm1,
    const float* __restrict__ bm2, float* __restrict__ out, int M) {
  __shared__ unsigned short smem[24576];
  unsigned short* W2s = &smem[15360];
  int tid = threadIdx.x;
  int lane = tid & 63, w = tid >> 6;
  int col16 = lane & 15, quad = lane >> 4;
  int row0 = blockIdx.x * 128;
  const unsigned short* Ag = (const unsigned short*)A;
  const unsigned short* Bg = (const unsigned short*)Wm1t;
  const unsigned short* W2g = (const unsigned short*)Wm2t;

#pragma unroll
  for (int c = tid; c < 1024; c += 256) {
    int r = c >> 3, ko = (c & 7) << 3;
    ushort8 v = {};
    if (r < 121) v = *(const ushort8*)(W2g + (size_t)r * 64 + ko);
    *(ushort8*)(&W2s[r * TS + ko]) = v;
  }

  int ar0 = tid >> 2, ako = (tid & 3) << 3;
  int agr0 = row0 + ar0;       if (agr0 >= M) agr0 = M - 1;
  int agr1 = row0 + ar0 + 64;  if (agr1 >= M) agr1 = M - 1;
  const unsigned short* aga0 = Ag + (size_t)agr0 * 256 + ako;
  const unsigned short* aga1 = Ag + (size_t)agr1 * 256 + ako;
  int br = tid >> 2, bko = (tid & 3) << 3;
  const unsigned short* bga = Bg + (size_t)br * 256 + bko;

  f32x4 acc1[2][4] = {};
  ushort8 pa0, pa1, pbv;
  pa0 = *(const ushort8*)(aga0);
  pa1 = *(const ushort8*)(aga1);
  pbv = *(const ushort8*)(bga);
  *(ushort8*)(&smem[ar0 * PK + ako]) = pa0;
  *(ushort8*)(&smem[(ar0 + 64) * PK + ako]) = pa1;
  *(ushort8*)(&smem[10240 + br * PK + bko]) = pbv;
  __syncthreads();

  for (int it = 0; it < 8; ++it) {
    int cur = it & 1, nxt = cur ^ 1;
    unsigned short* Asc = &smem[cur * 5120];
    unsigned short* Bsc = &smem[10240 + cur * 2560];
    int k1 = (it + 1) << 5;
    if (it + 1 < 8) {
      pa0 = *(const ushort8*)(aga0 + k1);
      pa1 = *(const ushort8*)(aga1 + k1);
      pbv = *(const ushort8*)(bga + k1);
    }
    bf16x8 a[2], b[4];
#pragma unroll
    for (int i = 0; i < 2; i++)
      a[i] = *(const bf16x8*)(&Asc[(w * 32 + i * 16 + col16) * PK + quad * 8]);
#pragma unroll
    for (int j = 0; j < 4; j++)
      b[j] = *(const bf16x8*)(&Bsc[(j * 16 + col16) * PK + quad * 8]);
#pragma unroll
    for (int i = 0; i < 2; i++)
#pragma unroll
      for (int j = 0; j < 4; j++)
        acc1[i][j] = __builtin_amdgcn_mfma_f32_16x16x32_bf16(a[i], b[j], acc1[i][j], 0, 0, 0);
    if (it + 1 < 8) {
      unsigned short* Asn = &smem[nxt * 5120];
      unsigned short* Bsn = &smem[10240 + nxt * 2560];
      *(ushort8*)(&Asn[ar0 * PK + ako]) = pa0;
      *(ushort8*)(&Asn[(ar0 + 64) * PK + ako]) = pa1;
      *(ushort8*)(&Bsn[br * PK + bko]) = pbv;
    }
    __syncthreads();
  }

  unsigned short* T = &smem[0];
#pragma unroll
  for (int i = 0; i < 2; i++) {
#pragma unroll
    for (int j = 0; j < 4; j++) {
      int col = j * 16 + col16;
      float bv = bm1[col];
#pragma unroll
      for (int r = 0; r < 4; r++) {
        int rl = w * 32 + i * 16 + quad * 4 + r;
        __hip_bfloat16 hv = __float2bfloat16(acc1[i][j][r] + bv);
        T[rl * TS + col] = *reinterpret_cast<unsigned short*>(&hv);
      }
    }
  }
  __syncthreads();

  int wm2 = w & 1, wn2 = w >> 1;
  f32x4 acc2[4][4] = {};
#pragma unroll
  for (int kk = 0; kk < 2; kk++) {
    bf16x8 a[4], b[4];
#pragma unroll
    for (int i = 0; i < 4; i++)
      a[i] = *(const bf16x8*)(&T[(wm2 * 64 + i * 16 + col16) * TS + kk * 32 + quad * 8]);
#pragma unroll
    for (int j = 0; j < 4; j++)
      b[j] = *(const bf16x8*)(&W2s[(wn2 * 64 + j * 16 + col16) * TS + kk * 32 + quad * 8]);
#pragma unroll
    for (int i = 0; i < 4; i++)
#pragma unroll
      for (int j = 0; j < 4; j++)
        acc2[i][j] = __builtin_amdgcn_mfma_f32_16x16x32_bf16(a[i], b[j], acc2[i][j], 0, 0, 0);
  }
#pragma unroll
  for (int i = 0; i < 4; i++) {
#pragma unroll
    for (int j = 0; j < 4; j++) {
      int gc = wn2 * 64 + j * 16 + col16;
      if (gc >= 121) continue;
      float bv = bm2[gc];
      int grb = row0 + wm2 * 64 + i * 16 + quad * 4;
#pragma unroll
      for (int r = 0; r < 4; r++) {
        int gr = grb + r;
        if (gr >= M) continue;
        float v = acc2[i][j][r] + bv;
        out[(size_t)gr * 121 + gc] = 1.f / (1.f + __expf(-v));
      }
    }
  }
}

// ---------------------------------------------------------------------------
// setup: x cast + all weight transposes + slot/cursor init, one kernel.
// ---------------------------------------------------------------------------
__global__ void setup_all(const float* __restrict__ x, __hip_bfloat16* __restrict__ xb,
                          const float* __restrict__ W1, const float* __restrict__ W2,
                          const float* __restrict__ Wm1, const float* __restrict__ Wm2,
                          __hip_bfloat16* __restrict__ W1t, __hip_bfloat16* __restrict__ W2t,
                          __hip_bfloat16* __restrict__ Wm1t, __hip_bfloat16* __restrict__ Wm2t,
                          int* __restrict__ cur, int* __restrict__ slots,
                          int n, int castBlocks, int prepBlocks) {
  int b = blockIdx.x;
  int tid = threadIdx.x;
  if (b < castBlocks) {  // cast x -> xb (float4 -> bf16x4)
    int i = b * 256 + tid;
    if (i < n * 32) {
      float4 v = *(const float4*)(x + 4 * (size_t)i);
      uint2 pk;
      pk.x = packbf2(v.x, v.y);
      pk.y = packbf2(v.z, v.w);
      *(uint2*)((unsigned*)xb + 2 * (size_t)i) = pk;
    }
    return;
  }
  b -= castBlocks;
  if (b < prepBlocks) {  // weight transposes
    int i = b * 256 + tid;
    if (i < 128 * 256) {
      int nn = i / 128, kk = i - nn * 128;
      W1t[i] = __float2bfloat16(W1[(size_t)kk * 256 + nn]);
      return;
    }
    i -= 128 * 256;
    if (i < 256 * 256) {
      int nn = i / 256, kk = i - nn * 256;
      W2t[i] = __float2bfloat16(W2[(size_t)kk * 256 + nn]);
      return;
    }
    i -= 256 * 256;
    if (i < 256 * 64) {
      int nn = i / 256, kk = i - nn * 256;
      Wm1t[i] = __float2bfloat16(Wm1[(size_t)kk * 64 + nn]);
      return;
    }
    i -= 256 * 64;
    if (i < 64 * 121) {
      int nn = i / 64, kk = i - nn * 64;
      Wm2t[i] = __float2bfloat16(Wm2[(size_t)kk * 121 + nn]);
    }
    return;
  }
  b -= prepBlocks;
  {  // slot init: self-loop in slot 0, cursor = 1
    int i = b * 256 + tid;
    if (i < n) {
      cur[i] = 1;
      slots[(size_t)i << SLOG] = i;
    }
  }
}

// fill adjacency slots (dst-bucketed, unordered)
__global__ void slot_fill(const int* __restrict__ ei, int E,
                          int* __restrict__ cur, int* __restrict__ slots) {
  int i = blockIdx.x * 256 + threadIdx.x;
  if (i >= E) return;
  int s = ei[i], d = ei[E + i];
  int pos = atomicAdd(&cur[d], 1);
  slots[((size_t)d << SLOG) + pos] = s;
}

// ---------------------------------------------------------------------------
// GAT aggregation — R9 proven body, unchanged (64.5us/dispatch, at the ~60us
// L3-fabric floor: FETCH 209MB = 8 XCD x 26MB compulsory @3.5TB/s. R10
// pipelining -6%, R12 slicing -188%, R13 atomic-gmax -44us total: all
// reverted).
// ---------------------------------------------------------------------------
__global__ void __launch_bounds__(256) gat_aggregate(
    const __hip_bfloat16* __restrict__ hb, const float* __restrict__ a_src,
    const float* __restrict__ a_dst, const int* __restrict__ cnt_arr,
    const int* __restrict__ slots, const float* __restrict__ bias,
    const float* __restrict__ gmaxf, int goff,
    __hip_bfloat16* __restrict__ out, int n) {
  __shared__ float plds[4][256];
  int wid = threadIdx.x >> 6;
  int lane = threadIdx.x & 63;
  int half = lane >> 5;
  int l32 = lane & 31;
  int qh = l32 >> 3;
  int node = (blockIdx.x << 2) + wid;
  if (node >= n) return;
  float4 adv = *(const float4*)(a_dst + (size_t)node * 4);
  float m0 = gmaxf[goff + 0] + adv.x; m0 = fmaxf(m0, NEG_SLOPE * m0);
  float m1 = gmaxf[goff + 1] + adv.y; m1 = fmaxf(m1, NEG_SLOPE * m1);
  float m2 = gmaxf[goff + 2] + adv.z; m2 = fmaxf(m2, NEG_SLOPE * m2);
  float m3 = gmaxf[goff + 3] + adv.w; m3 = fmaxf(m3, NEG_SLOPE * m3);
  int cntN = __builtin_amdgcn_readfirstlane(cnt_arr[node]);
  int beg = node << SLOG;
  const uint4* hw4 = (const uint4*)hb;

  float lq = 0.f;
  float c0 = 0.f, c1 = 0.f, c2 = 0.f, c3 = 0.f;
  float c4 = 0.f, c5 = 0.f, c6 = 0.f, c7 = 0.f;

  for (int cbeg = 0; cbeg < cntN; cbeg += 64) {
    int cnt = cntN - cbeg; if (cnt > 64) cnt = 64;
    int eidx = beg + cbeg + (lane < cnt ? lane : cnt - 1);
    int s_l = slots[eidx];
    float4 as = *(const float4*)(a_src + (size_t)s_l * 4);
    float v0 = as.x + adv.x; v0 = fmaxf(v0, NEG_SLOPE * v0);
    float v1 = as.y + adv.y; v1 = fmaxf(v1, NEG_SLOPE * v1);
    float v2 = as.z + adv.z; v2 = fmaxf(v2, NEG_SLOPE * v2);
    float v3 = as.w + adv.w; v3 = fmaxf(v3, NEG_SLOPE * v3);
    float p0 = __expf(v0 - m0), p1 = __expf(v1 - m1);
    float p2 = __expf(v2 - m2), p3 = __expf(v3 - m3);
    *(float4*)&plds[wid][lane * 4] = make_float4(p0, p1, p2, p3);
    __builtin_amdgcn_s_waitcnt(0);

    auto step = [&](int j) {
      int jj = j + half;
      bool dup = jj >= cnt;
      int jc = dup ? cnt - 1 : jj;
      int sj = __shfl(s_l, jc);
      float pq = plds[wid][jc * 4 + qh];
      if (dup) pq = 0.f;
      uint4 d = hw4[(size_t)sj * 32 + l32];
      c0 += pq * bflo(d.x); c1 += pq * bfhi(d.x);
      c2 += pq * bflo(d.y); c3 += pq * bfhi(d.y);
      c4 += pq * bflo(d.z); c5 += pq * bfhi(d.z);
      c6 += pq * bflo(d.w); c7 += pq * bfhi(d.w);
      lq += pq;
    };
    // fully-predicated unrolled loop (R9 proven): no rolled tail.
    for (int j = 0; j < cnt; j += 8) { step(j); step(j + 2); step(j + 4); step(j + 6); }
  }

  lq += __shfl_xor(lq, 32);
  c0 += __shfl_xor(c0, 32); c1 += __shfl_xor(c1, 32);
  c2 += __shfl_xor(c2, 32); c3 += __shfl_xor(c3, 32);
  c4 += __shfl_xor(c4, 32); c5 += __shfl_xor(c5, 32);
  c6 += __shfl_xor(c6, 32); c7 += __shfl_xor(c7, 32);

  if (half == 0) {
    float4 bA = *(const float4*)(bias + 8 * l32);
    float4 bB = *(const float4*)(bias + 8 * l32 + 4);
    float rq = 1.f / (lq + EPS);
    float o0 = fmaxf(c0 * rq + bA.x, 0.f);
    float o1 = fmaxf(c1 * rq + bA.y, 0.f);
    float o2 = fmaxf(c2 * rq + bA.z, 0.f);
    float o3 = fmaxf(c3 * rq + bA.w, 0.f);
    float o4 = fmaxf(c4 * rq + bB.x, 0.f);
    float o5 = fmaxf(c5 * rq + bB.y, 0.f);
    float o6 = fmaxf(c6 * rq + bB.z, 0.f);
    float o7 = fmaxf(c7 * rq + bB.w, 0.f);
    uint4 pk;
    pk.x = packbf2(o0, o1);
    pk.y = packbf2(o2, o3);
    pk.z = packbf2(o4, o5);
    pk.w = packbf2(o6, o7);
    *(uint4*)((unsigned*)out + (size_t)node * 128 + l32 * 4) = pk;
  }
}

// ---------------------------------------------------------------------------
extern "C" void kernel_launch(void* const* d_in, const int* in_sizes, int n_in,
                              void* d_out, int out_size, void* d_ws, size_t ws_size,
                              hipStream_t stream) {
  const float* x      = (const float*)d_in[0];
  const int*   ei     = (const int*)d_in[1];
  const float* W1     = (const float*)d_in[2];
  const float* att_s1 = (const float*)d_in[3];
  const float* att_d1 = (const float*)d_in[4];
  const float* b1     = (const float*)d_in[5];
  const float* W2     = (const float*)d_in[6];
  const float* att_s2 = (const float*)d_in[7];
  const float* att_d2 = (const float*)d_in[8];
  const float* b2     = (const float*)d_in[9];
  const float* Wm1    = (const float*)d_in[10];
  const float* bm1    = (const float*)d_in[11];
  const float* Wm2    = (const float*)d_in[12];
  const float* bm2    = (const float*)d_in[13];
  float* out = (float*)d_out;

  int n = in_sizes[0] / 128;   // 50000
  int E = in_sizes[1] / 2;     // 800000

  char* ws = (char*)d_ws;
  size_t off = 0;
  auto carve = [&](size_t bytes) {
    char* p = ws + off;
    off += (bytes + 255) & ~(size_t)255;
    return p;
  };
  __hip_bfloat16* hb   = (__hip_bfloat16*)carve((size_t)n * HC * 2);
  __hip_bfloat16* aggb = (__hip_bfloat16*)carve((size_t)n * HC * 2);
  __hip_bfloat16* xb   = (__hip_bfloat16*)carve((size_t)n * 128 * 2);
  __hip_bfloat16* W1t  = (__hip_bfloat16*)carve((size_t)128 * HC * 2);
  __hip_bfloat16* W2t  = (__hip_bfloat16*)carve((size_t)HC * HC * 2);
  __hip_bfloat16* Wm1t = (__hip_bfloat16*)carve((size_t)HC * HID * 2);
  __hip_bfloat16* Wm2t = (__hip_bfloat16*)carve((size_t)HID * 121 * 2);
  float* as    = (float*)carve((size_t)n * HEADS * 4);
  float* ad    = (float*)carve((size_t)n * HEADS * 4);
  int*   cur   = (int*)carve((size_t)n * 4);
  int*   slots = (int*)carve(((size_t)n << SLOG) * 4);
  float* blockmax = (float*)carve((size_t)((n + 63) / 64) * 4 * 4);
  float* gmaxf    = (float*)carve((size_t)8 * 4);
  (void)ws_size;

  int rows64 = (n + 63) / 64;                       // 782 conv blocks
  int castBlocks = (n * 32 + 255) / 256;            // 6250
  int prepBlocks = (122432 + 255) / 256;            // 479
  int slotBlocks = (n + 255) / 256;                 // 196

  // 1: setup (cast + transposes + slot init)
  setup_all<<<castBlocks + prepBlocks + slotBlocks, 256, 0, stream>>>(
      x, xb, W1, W2, Wm1, Wm2, W1t, W2t, Wm1t, Wm2t, cur, slots,
      n, castBlocks, prepBlocks);
  // 2: adjacency fill
  slot_fill<<<(E + 255) / 256, 256, 0, stream>>>(ei, E, cur, slots);

  // 3: conv1 (+ fused attn coefs), 512-thread blocks
  conv_gemm_attn<<<rows64, 512, 0, stream>>>(
      xb, W1t, hb, att_s1, att_d1, as, ad, blockmax, n, 128);
  // 4: gmax reduce
  reduce_gmax<<<1, 256, 0, stream>>>(blockmax, gmaxf, 0, rows64);
  // 5: aggregate 1
  gat_aggregate<<<(n + 3) / 4, 256, 0, stream>>>(hb, as, ad, cur, slots, b1, gmaxf, 0, aggb, n);

  // 6: conv2
  conv_gemm_attn<<<rows64, 512, 0, stream>>>(
      aggb, W2t, hb, att_s2, att_d2, as, ad, blockmax, n, HC);
  // 7: gmax reduce
  reduce_gmax<<<1, 256, 0, stream>>>(blockmax, gmaxf, 4, rows64);
  // 8: aggregate 2
  gat_aggregate<<<(n + 3) / 4, 256, 0, stream>>>(hb, as, ad, cur, slots, b2, gmaxf, 4, aggb, n);

  // 9: post_mp
  postmp_fused<<<(n + 127) / 128, 256, 0, stream>>>(aggb, Wm1t, Wm2t, bm1, bm2, out, n);
}

// Round 12
// 346.983 us; speedup vs baseline: 1.6438x; 1.0300x over previous
//
#include <hip/hip_runtime.h>
#include <hip/hip_bf16.h>
#include <float.h>

#define HEADS 4
#define HID 64
#define HC 256   // HEADS*HID
#define NEG_SLOPE 0.2f
#define EPS 1e-16f
#define SLOG 7           // log2 slots per node
#define SLOTS 128        // fixed adjacency slots per node (max in-deg ~45)

typedef short bf16x8 __attribute__((ext_vector_type(8)));
typedef float f32x4 __attribute__((ext_vector_type(4)));
typedef unsigned short ushort8 __attribute__((ext_vector_type(8)));

__device__ __forceinline__ float bflo(unsigned u) { return __uint_as_float(u << 16); }
__device__ __forceinline__ float bfhi(unsigned u) { return __uint_as_float(u & 0xffff0000u); }
__device__ __forceinline__ unsigned packbf2(float a, float b) {
  __hip_bfloat16 ha = __float2bfloat16(a), hb = __float2bfloat16(b);
  unsigned short ua = *reinterpret_cast<unsigned short*>(&ha);
  unsigned short ub = *reinterpret_cast<unsigned short*>(&hb);
  return (unsigned)ua | ((unsigned)ub << 16);
}

#define PK 40  // padded LDS row stride (bf16 elems) — proven conflict-light

// ---------------------------------------------------------------------------
// Conv GEMM — R16: R15's proven 512-thread body (64x256 tile, 51KB LDS,
// 16-24 waves/CU) with two structural trims:
//  * template<F32A>: conv1 casts x fp32->bf16 in staging registers — kills
//    the separate cast pass (38.4MB traffic -> 0) and the xb buffer.
//  * blockmax epilogue + reduce_gmax REMOVED: aggregate now computes the
//    true per-node segment max in-wave (it already loads every edge score).
// ---------------------------------------------------------------------------
template<bool F32A>
__global__ void __launch_bounds__(512) conv_gemm_attn(
    const void* __restrict__ Ain, const __hip_bfloat16* __restrict__ Bt,
    __hip_bfloat16* __restrict__ Cb,
    const float* __restrict__ att_s, const float* __restrict__ att_d,
    float* __restrict__ a_s, float* __restrict__ a_d, int M, int K) {
  __shared__ unsigned short As[2][64 * PK];
  __shared__ unsigned short Bs[2][256 * PK];
  int tid = threadIdx.x;
  int lane = tid & 63, w = tid >> 6;        // w: 0..7
  int col16 = lane & 15, quad = lane >> 4;
  int r0 = (w >> 2) * 32;                   // row half: 0 or 32
  int c0 = (w & 3) * 64;                    // head * 64
  int row0 = blockIdx.x * 64;
  const unsigned short* Ag = (const unsigned short*)Ain;
  const float* Af = (const float*)Ain;
  const unsigned short* Bg = (const unsigned short*)Bt;

  bool doA = tid < 256;
  int ar = (tid & 255) >> 2;                // 0..63
  int ako = (tid & 3) << 3;                 // 0,8,16,24
  int agr = row0 + ar; if (agr >= M) agr = M - 1;
  const unsigned short* aga = Ag + (size_t)agr * K + ako;
  const float* agaf = Af + (size_t)agr * K + ako;

  auto loadA = [&](int koff) -> ushort8 {
    if constexpr (F32A) {
      float4 f0 = *(const float4*)(agaf + koff);
      float4 f1 = *(const float4*)(agaf + koff + 4);
      unsigned p0 = packbf2(f0.x, f0.y), p1 = packbf2(f0.z, f0.w);
      unsigned p2 = packbf2(f1.x, f1.y), p3 = packbf2(f1.z, f1.w);
      ushort8 r;
      r[0] = (unsigned short)p0; r[1] = (unsigned short)(p0 >> 16);
      r[2] = (unsigned short)p1; r[3] = (unsigned short)(p1 >> 16);
      r[4] = (unsigned short)p2; r[5] = (unsigned short)(p2 >> 16);
      r[6] = (unsigned short)p3; r[7] = (unsigned short)(p3 >> 16);
      return r;
    } else {
      return *(const ushort8*)(aga + koff);
    }
  };

  f32x4 acc[2][4] = {};
  int niter = K >> 5;

  ushort8 pa, pb[2];
  if (doA) pa = loadA(0);
#pragma unroll
  for (int p = 0; p < 2; p++) {
    int i2 = tid + (p << 9);
    int br = i2 >> 2, bko = (i2 & 3) << 3;
    pb[p] = *(const ushort8*)(Bg + (size_t)br * K + bko);
  }
  if (doA) *(ushort8*)(&As[0][ar * PK + ako]) = pa;
#pragma unroll
  for (int p = 0; p < 2; p++) {
    int i2 = tid + (p << 9);
    int br = i2 >> 2, bko = (i2 & 3) << 3;
    *(ushort8*)(&Bs[0][br * PK + bko]) = pb[p];
  }
  __syncthreads();

  for (int it = 0; it < niter; ++it) {
    int cur = it & 1, nxt = cur ^ 1;
    int k1 = (it + 1) << 5;
    if (it + 1 < niter) {
      if (doA) pa = loadA(k1);
#pragma unroll
      for (int p = 0; p < 2; p++) {
        int i2 = tid + (p << 9);
        int br = i2 >> 2, bko = (i2 & 3) << 3;
        pb[p] = *(const ushort8*)(Bg + (size_t)br * K + k1 + bko);
      }
    }
    bf16x8 a[2], b[4];
#pragma unroll
    for (int i = 0; i < 2; i++)
      a[i] = *(const bf16x8*)(&As[cur][(r0 + i * 16 + col16) * PK + quad * 8]);
#pragma unroll
    for (int j = 0; j < 4; j++)
      b[j] = *(const bf16x8*)(&Bs[cur][(c0 + j * 16 + col16) * PK + quad * 8]);
#pragma unroll
    for (int i = 0; i < 2; i++)
#pragma unroll
      for (int j = 0; j < 4; j++)
        acc[i][j] = __builtin_amdgcn_mfma_f32_16x16x32_bf16(a[i], b[j], acc[i][j], 0, 0, 0);
    if (it + 1 < niter) {
      if (doA) *(ushort8*)(&As[nxt][ar * PK + ako]) = pa;
#pragma unroll
      for (int p = 0; p < 2; p++) {
        int i2 = tid + (p << 9);
        int br = i2 >> 2, bko = (i2 & 3) << 3;
        *(ushort8*)(&Bs[nxt][br * PK + bko]) = pb[p];
      }
    }
    __syncthreads();
  }

#pragma unroll
  for (int i = 0; i < 2; i++) {
#pragma unroll
    for (int j = 0; j < 4; j++) {
      int gc = c0 + j * 16 + col16;
      int grb = row0 + r0 + i * 16 + quad * 4;
#pragma unroll
      for (int r = 0; r < 4; r++) {
        int gr = grb + r;
        if (gr < M) Cb[(size_t)gr * 256 + gc] = __float2bfloat16(acc[i][j][r]);
      }
    }
  }

  float ws4[4], wd4[4];
#pragma unroll
  for (int j = 0; j < 4; j++) {
    ws4[j] = att_s[c0 + j * 16 + col16];
    wd4[j] = att_d[c0 + j * 16 + col16];
  }
#pragma unroll
  for (int i = 0; i < 2; i++) {
#pragma unroll
    for (int r = 0; r < 4; r++) {
      float vs = 0.f, vd = 0.f;
#pragma unroll
      for (int j = 0; j < 4; j++) {
        vs += acc[i][j][r] * ws4[j];
        vd += acc[i][j][r] * wd4[j];
      }
#pragma unroll
      for (int off = 1; off < 16; off <<= 1) {
        vs += __shfl_xor(vs, off);
        vd += __shfl_xor(vd, off);
      }
      int gr = row0 + r0 + i * 16 + quad * 4 + r;
      if (col16 == 0 && gr < M) {
        a_s[(size_t)gr * 4 + (w & 3)] = vs;
        a_d[(size_t)gr * 4 + (w & 3)] = vd;
      }
    }
  }
}

// ---------------------------------------------------------------------------
// Fused post_mp with dbuf stage 1 (R7 proven).
// ---------------------------------------------------------------------------
#define TS 72

__global__ void __launch_bounds__(256) postmp_fused(
    const __hip_bfloat16* __restrict__ A, const __hip_bfloat16* __restrict__ Wm1t,
    const __hip_bfloat16* __restrict__ Wm2t, const float* __restrict__ bm1,
    const float* __restrict__ bm2, float* __restrict__ out, int M) {
  __shared__ unsigned short smem[24576];
  unsigned short* W2s = &smem[15360];
  int tid = threadIdx.x;
  int lane = tid & 63, w = tid >> 6;
  int col16 = lane & 15, quad = lane >> 4;
  int row0 = blockIdx.x * 128;
  const unsigned short* Ag = (const unsigned short*)A;
  const unsigned short* Bg = (const unsigned short*)Wm1t;
  const unsigned short* W2g = (const unsigned short*)Wm2t;

#pragma unroll
  for (int c = tid; c < 1024; c += 256) {
    int r = c >> 3, ko = (c & 7) << 3;
    ushort8 v = {};
    if (r < 121) v = *(const ushort8*)(W2g + (size_t)r * 64 + ko);
    *(ushort8*)(&W2s[r * TS + ko]) = v;
  }

  int ar0 = tid >> 2, ako = (tid & 3) << 3;
  int agr0 = row0 + ar0;       if (agr0 >= M) agr0 = M - 1;
  int agr1 = row0 + ar0 + 64;  if (agr1 >= M) agr1 = M - 1;
  const unsigned short* aga0 = Ag + (size_t)agr0 * 256 + ako;
  const unsigned short* aga1 = Ag + (size_t)agr1 * 256 + ako;
  int br = tid >> 2, bko = (tid & 3) << 3;
  const unsigned short* bga = Bg + (size_t)br * 256 + bko;

  f32x4 acc1[2][4] = {};
  ushort8 pa0, pa1, pbv;
  pa0 = *(const ushort8*)(aga0);
  pa1 = *(const ushort8*)(aga1);
  pbv = *(const ushort8*)(bga);
  *(ushort8*)(&smem[ar0 * PK + ako]) = pa0;
  *(ushort8*)(&smem[(ar0 + 64) * PK + ako]) = pa1;
  *(ushort8*)(&smem[10240 + br * PK + bko]) = pbv;
  __syncthreads();

  for (int it = 0; it < 8; ++it) {
    int cur = it & 1, nxt = cur ^ 1;
    unsigned short* Asc = &smem[cur * 5120];
    unsigned short* Bsc = &smem[10240 + cur * 2560];
    int k1 = (it + 1) << 5;
    if (it + 1 < 8) {
      pa0 = *(const ushort8*)(aga0 + k1);
      pa1 = *(const ushort8*)(aga1 + k1);
      pbv = *(const ushort8*)(bga + k1);
    }
    bf16x8 a[2], b[4];
#pragma unroll
    for (int i = 0; i < 2; i++)
      a[i] = *(const bf16x8*)(&Asc[(w * 32 + i * 16 + col16) * PK + quad * 8]);
#pragma unroll
    for (int j = 0; j < 4; j++)
      b[j] = *(const bf16x8*)(&Bsc[(j * 16 + col16) * PK + quad * 8]);
#pragma unroll
    for (int i = 0; i < 2; i++)
#pragma unroll
      for (int j = 0; j < 4; j++)
        acc1[i][j] = __builtin_amdgcn_mfma_f32_16x16x32_bf16(a[i], b[j], acc1[i][j], 0, 0, 0);
    if (it + 1 < 8) {
      unsigned short* Asn = &smem[nxt * 5120];
      unsigned short* Bsn = &smem[10240 + nxt * 2560];
      *(ushort8*)(&Asn[ar0 * PK + ako]) = pa0;
      *(ushort8*)(&Asn[(ar0 + 64) * PK + ako]) = pa1;
      *(ushort8*)(&Bsn[br * PK + bko]) = pbv;
    }
    __syncthreads();
  }

  unsigned short* T = &smem[0];
#pragma unroll
  for (int i = 0; i < 2; i++) {
#pragma unroll
    for (int j = 0; j < 4; j++) {
      int col = j * 16 + col16;
      float bv = bm1[col];
#pragma unroll
      for (int r = 0; r < 4; r++) {
        int rl = w * 32 + i * 16 + quad * 4 + r;
        __hip_bfloat16 hv = __float2bfloat16(acc1[i][j][r] + bv);
        T[rl * TS + col] = *reinterpret_cast<unsigned short*>(&hv);
      }
    }
  }
  __syncthreads();

  int wm2 = w & 1, wn2 = w >> 1;
  f32x4 acc2[4][4] = {};
#pragma unroll
  for (int kk = 0; kk < 2; kk++) {
    bf16x8 a[4], b[4];
#pragma unroll
    for (int i = 0; i < 4; i++)
      a[i] = *(const bf16x8*)(&T[(wm2 * 64 + i * 16 + col16) * TS + kk * 32 + quad * 8]);
#pragma unroll
    for (int j = 0; j < 4; j++)
      b[j] = *(const bf16x8*)(&W2s[(wn2 * 64 + j * 16 + col16) * TS + kk * 32 + quad * 8]);
#pragma unroll
    for (int i = 0; i < 4; i++)
#pragma unroll
      for (int j = 0; j < 4; j++)
        acc2[i][j] = __builtin_amdgcn_mfma_f32_16x16x32_bf16(a[i], b[j], acc2[i][j], 0, 0, 0);
  }
#pragma unroll
  for (int i = 0; i < 4; i++) {
#pragma unroll
    for (int j = 0; j < 4; j++) {
      int gc = wn2 * 64 + j * 16 + col16;
      if (gc >= 121) continue;
      float bv = bm2[gc];
      int grb = row0 + wm2 * 64 + i * 16 + quad * 4;
#pragma unroll
      for (int r = 0; r < 4; r++) {
        int gr = grb + r;
        if (gr >= M) continue;
        float v = acc2[i][j][r] + bv;
        out[(size_t)gr * 121 + gc] = 1.f / (1.f + __expf(-v));
      }
    }
  }
}

// ---------------------------------------------------------------------------
// setup: weight transposes + slot/cursor init (x cast now fused into conv1).
// ---------------------------------------------------------------------------
__global__ void setup_all(const float* __restrict__ W1, const float* __restrict__ W2,
                          const float* __restrict__ Wm1, const float* __restrict__ Wm2,
                          __hip_bfloat16* __restrict__ W1t, __hip_bfloat16* __restrict__ W2t,
                          __hip_bfloat16* __restrict__ Wm1t, __hip_bfloat16* __restrict__ Wm2t,
                          int* __restrict__ cur, int* __restrict__ slots,
                          int n, int prepBlocks) {
  int b = blockIdx.x;
  int tid = threadIdx.x;
  if (b < prepBlocks) {  // weight transposes
    int i = b * 256 + tid;
    if (i < 128 * 256) {
      int nn = i / 128, kk = i - nn * 128;
      W1t[i] = __float2bfloat16(W1[(size_t)kk * 256 + nn]);
      return;
    }
    i -= 128 * 256;
    if (i < 256 * 256) {
      int nn = i / 256, kk = i - nn * 256;
      W2t[i] = __float2bfloat16(W2[(size_t)kk * 256 + nn]);
      return;
    }
    i -= 256 * 256;
    if (i < 256 * 64) {
      int nn = i / 256, kk = i - nn * 256;
      Wm1t[i] = __float2bfloat16(Wm1[(size_t)kk * 64 + nn]);
      return;
    }
    i -= 256 * 64;
    if (i < 64 * 121) {
      int nn = i / 64, kk = i - nn * 64;
      Wm2t[i] = __float2bfloat16(Wm2[(size_t)kk * 121 + nn]);
    }
    return;
  }
  b -= prepBlocks;
  {  // slot init: self-loop in slot 0, cursor = 1
    int i = b * 256 + tid;
    if (i < n) {
      cur[i] = 1;
      slots[(size_t)i << SLOG] = i;
    }
  }
}

// fill adjacency slots (dst-bucketed, unordered)
__global__ void slot_fill(const int* __restrict__ ei, int E,
                          int* __restrict__ cur, int* __restrict__ slots) {
  int i = blockIdx.x * 256 + threadIdx.x;
  if (i >= E) return;
  int s = ei[i], d = ei[E + i];
  int pos = atomicAdd(&cur[d], 1);
  slots[((size_t)d << SLOG) + pos] = s;
}

// ---------------------------------------------------------------------------
// GAT aggregation — R16: R9 proven gather body + TRUE per-node segment max
// computed in-wave (reference semantics; removes the global-max round-trip
// and both reduce_gmax dispatches). cnt<=64 (max in-deg ~45) keeps edge
// scores in registers; generic 2-pass fallback for cnt>64.
// Gather loop / fetch behavior unchanged: 64.5us at the L3-fabric floor
// (FETCH 209MB = 8 XCD x 26MB @3.5TB/s; R10/R12/R13 alternatives refuted).
// ---------------------------------------------------------------------------
__global__ void __launch_bounds__(256) gat_aggregate(
    const __hip_bfloat16* __restrict__ hb, const float* __restrict__ a_src,
    const float* __restrict__ a_dst, const int* __restrict__ cnt_arr,
    const int* __restrict__ slots, const float* __restrict__ bias,
    __hip_bfloat16* __restrict__ out, int n) {
  __shared__ float plds[4][256];
  int wid = threadIdx.x >> 6;
  int lane = threadIdx.x & 63;
  int half = lane >> 5;
  int l32 = lane & 31;
  int qh = l32 >> 3;
  int node = (blockIdx.x << 2) + wid;
  if (node >= n) return;
  float4 adv = *(const float4*)(a_dst + (size_t)node * 4);
  int cntN = __builtin_amdgcn_readfirstlane(cnt_arr[node]);
  int beg = node << SLOG;
  const uint4* hw4 = (const uint4*)hb;

  float lq = 0.f;
  float c0 = 0.f, c1 = 0.f, c2 = 0.f, c3 = 0.f;
  float c4 = 0.f, c5 = 0.f, c6 = 0.f, c7 = 0.f;

  auto gather = [&](int s_l, int cnt) {
    auto step = [&](int j) {
      int jj = j + half;
      bool dup = jj >= cnt;
      int jc = dup ? cnt - 1 : jj;
      int sj = __shfl(s_l, jc);
      float pq = plds[wid][jc * 4 + qh];
      if (dup) pq = 0.f;
      uint4 d = hw4[(size_t)sj * 32 + l32];
      c0 += pq * bflo(d.x); c1 += pq * bfhi(d.x);
      c2 += pq * bflo(d.y); c3 += pq * bfhi(d.y);
      c4 += pq * bflo(d.z); c5 += pq * bfhi(d.z);
      c6 += pq * bflo(d.w); c7 += pq * bfhi(d.w);
      lq += pq;
    };
    // fully-predicated unrolled loop (R9 proven): no rolled tail.
    for (int j = 0; j < cnt; j += 8) { step(j); step(j + 2); step(j + 4); step(j + 6); }
  };

  if (cntN <= 64) {
    // common path (max in-deg ~45): all edge scores live in the wave.
    int eidx = beg + (lane < cntN ? lane : cntN - 1);
    int s_l = slots[eidx];
    float4 as = *(const float4*)(a_src + (size_t)s_l * 4);
    float v0 = as.x + adv.x; v0 = fmaxf(v0, NEG_SLOPE * v0);
    float v1 = as.y + adv.y; v1 = fmaxf(v1, NEG_SLOPE * v1);
    float v2 = as.z + adv.z; v2 = fmaxf(v2, NEG_SLOPE * v2);
    float v3 = as.w + adv.w; v3 = fmaxf(v3, NEG_SLOPE * v3);
    // per-node segment max (dup lanes replicate real edge cnt-1 — harmless)
    float m0 = v0, m1 = v1, m2 = v2, m3 = v3;
#pragma unroll
    for (int off = 1; off < 64; off <<= 1) {
      m0 = fmaxf(m0, __shfl_xor(m0, off));
      m1 = fmaxf(m1, __shfl_xor(m1, off));
      m2 = fmaxf(m2, __shfl_xor(m2, off));
      m3 = fmaxf(m3, __shfl_xor(m3, off));
    }
    float p0 = __expf(v0 - m0), p1 = __expf(v1 - m1);
    float p2 = __expf(v2 - m2), p3 = __expf(v3 - m3);
    *(float4*)&plds[wid][lane * 4] = make_float4(p0, p1, p2, p3);
    __builtin_amdgcn_s_waitcnt(0);
    gather(s_l, cntN);
  } else {
    // rare generic path: pass 1 max over chunks, pass 2 exp+gather.
    float m0 = -FLT_MAX, m1 = -FLT_MAX, m2 = -FLT_MAX, m3 = -FLT_MAX;
    for (int cbeg = 0; cbeg < cntN; cbeg += 64) {
      int cnt = cntN - cbeg; if (cnt > 64) cnt = 64;
      int eidx = beg + cbeg + (lane < cnt ? lane : cnt - 1);
      int s_l = slots[eidx];
      float4 as = *(const float4*)(a_src + (size_t)s_l * 4);
      float v0 = as.x + adv.x; v0 = fmaxf(v0, NEG_SLOPE * v0);
      float v1 = as.y + adv.y; v1 = fmaxf(v1, NEG_SLOPE * v1);
      float v2 = as.z + adv.z; v2 = fmaxf(v2, NEG_SLOPE * v2);
      float v3 = as.w + adv.w; v3 = fmaxf(v3, NEG_SLOPE * v3);
      m0 = fmaxf(m0, v0); m1 = fmaxf(m1, v1);
      m2 = fmaxf(m2, v2); m3 = fmaxf(m3, v3);
    }
#pragma unroll
    for (int off = 1; off < 64; off <<= 1) {
      m0 = fmaxf(m0, __shfl_xor(m0, off));
      m1 = fmaxf(m1, __shfl_xor(m1, off));
      m2 = fmaxf(m2, __shfl_xor(m2, off));
      m3 = fmaxf(m3, __shfl_xor(m3, off));
    }
    for (int cbeg = 0; cbeg < cntN; cbeg += 64) {
      int cnt = cntN - cbeg; if (cnt > 64) cnt = 64;
      int eidx = beg + cbeg + (lane < cnt ? lane : cnt - 1);
      int s_l = slots[eidx];
      float4 as = *(const float4*)(a_src + (size_t)s_l * 4);
      float v0 = as.x + adv.x; v0 = fmaxf(v0, NEG_SLOPE * v0);
      float v1 = as.y + adv.y; v1 = fmaxf(v1, NEG_SLOPE * v1);
      float v2 = as.z + adv.z; v2 = fmaxf(v2, NEG_SLOPE * v2);
      float v3 = as.w + adv.w; v3 = fmaxf(v3, NEG_SLOPE * v3);
      float p0 = __expf(v0 - m0), p1 = __expf(v1 - m1);
      float p2 = __expf(v2 - m2), p3 = __expf(v3 - m3);
      *(float4*)&plds[wid][lane * 4] = make_float4(p0, p1, p2, p3);
      __builtin_amdgcn_s_waitcnt(0);
      gather(s_l, cnt);
    }
  }

  lq += __shfl_xor(lq, 32);
  c0 += __shfl_xor(c0, 32); c1 += __shfl_xor(c1, 32);
  c2 += __shfl_xor(c2, 32); c3 += __shfl_xor(c3, 32);
  c4 += __shfl_xor(c4, 32); c5 += __shfl_xor(c5, 32);
  c6 += __shfl_xor(c6, 32); c7 += __shfl_xor(c7, 32);

  if (half == 0) {
    float4 bA = *(const float4*)(bias + 8 * l32);
    float4 bB = *(const float4*)(bias + 8 * l32 + 4);
    float rq = 1.f / (lq + EPS);
    float o0 = fmaxf(c0 * rq + bA.x, 0.f);
    float o1 = fmaxf(c1 * rq + bA.y, 0.f);
    float o2 = fmaxf(c2 * rq + bA.z, 0.f);
    float o3 = fmaxf(c3 * rq + bA.w, 0.f);
    float o4 = fmaxf(c4 * rq + bB.x, 0.f);
    float o5 = fmaxf(c5 * rq + bB.y, 0.f);
    float o6 = fmaxf(c6 * rq + bB.z, 0.f);
    float o7 = fmaxf(c7 * rq + bB.w, 0.f);
    uint4 pk;
    pk.x = packbf2(o0, o1);
    pk.y = packbf2(o2, o3);
    pk.z = packbf2(o4, o5);
    pk.w = packbf2(o6, o7);
    *(uint4*)((unsigned*)out + (size_t)node * 128 + l32 * 4) = pk;
  }
}

// ---------------------------------------------------------------------------
extern "C" void kernel_launch(void* const* d_in, const int* in_sizes, int n_in,
                              void* d_out, int out_size, void* d_ws, size_t ws_size,
                              hipStream_t stream) {
  const float* x      = (const float*)d_in[0];
  const int*   ei     = (const int*)d_in[1];
  const float* W1     = (const float*)d_in[2];
  const float* att_s1 = (const float*)d_in[3];
  const float* att_d1 = (const float*)d_in[4];
  const float* b1     = (const float*)d_in[5];
  const float* W2     = (const float*)d_in[6];
  const float* att_s2 = (const float*)d_in[7];
  const float* att_d2 = (const float*)d_in[8];
  const float* b2     = (const float*)d_in[9];
  const float* Wm1    = (const float*)d_in[10];
  const float* bm1    = (const float*)d_in[11];
  const float* Wm2    = (const float*)d_in[12];
  const float* bm2    = (const float*)d_in[13];
  float* out = (float*)d_out;

  int n = in_sizes[0] / 128;   // 50000
  int E = in_sizes[1] / 2;     // 800000

  char* ws = (char*)d_ws;
  size_t off = 0;
  auto carve = [&](size_t bytes) {
    char* p = ws + off;
    off += (bytes + 255) & ~(size_t)255;
    return p;
  };
  __hip_bfloat16* hb   = (__hip_bfloat16*)carve((size_t)n * HC * 2);
  __hip_bfloat16* aggb = (__hip_bfloat16*)carve((size_t)n * HC * 2);
  __hip_bfloat16* W1t  = (__hip_bfloat16*)carve((size_t)128 * HC * 2);
  __hip_bfloat16* W2t  = (__hip_bfloat16*)carve((size_t)HC * HC * 2);
  __hip_bfloat16* Wm1t = (__hip_bfloat16*)carve((size_t)HC * HID * 2);
  __hip_bfloat16* Wm2t = (__hip_bfloat16*)carve((size_t)HID * 121 * 2);
  float* as    = (float*)carve((size_t)n * HEADS * 4);
  float* ad    = (float*)carve((size_t)n * HEADS * 4);
  int*   cur   = (int*)carve((size_t)n * 4);
  int*   slots = (int*)carve(((size_t)n << SLOG) * 4);
  (void)ws_size;

  int rows64 = (n + 63) / 64;                       // 782 conv blocks
  int prepBlocks = (122432 + 255) / 256;            // 479
  int slotBlocks = (n + 255) / 256;                 // 196

  // 1: setup (transposes + slot init; x cast fused into conv1)
  setup_all<<<prepBlocks + slotBlocks, 256, 0, stream>>>(
      W1, W2, Wm1, Wm2, W1t, W2t, Wm1t, Wm2t, cur, slots, n, prepBlocks);
  // 2: adjacency fill
  slot_fill<<<(E + 255) / 256, 256, 0, stream>>>(ei, E, cur, slots);

  // 3: conv1 (fp32 A, casts in staging regs) + fused attn coefs
  conv_gemm_attn<true><<<rows64, 512, 0, stream>>>(
      x, W1t, hb, att_s1, att_d1, as, ad, n, 128);
  // 4: aggregate 1 (per-node segment max in-wave)
  gat_aggregate<<<(n + 3) / 4, 256, 0, stream>>>(hb, as, ad, cur, slots, b1, aggb, n);

  // 5: conv2 (bf16 A)
  conv_gemm_attn<false><<<rows64, 512, 0, stream>>>(
      aggb, W2t, hb, att_s2, att_d2, as, ad, n, HC);
  // 6: aggregate 2
  gat_aggregate<<<(n + 3) / 4, 256, 0, stream>>>(hb, as, ad, cur, slots, b2, aggb, n);

  // 7: post_mp
  postmp_fused<<<(n + 127) / 128, 256, 0, stream>>>(aggb, Wm1t, Wm2t, bm1, bm2, out, n);
}